// Round 16
// baseline (186.547 us; speedup 1.0000x reference)
//
#include <hip/hip_runtime.h>
#include <hip/hip_bf16.h>

typedef unsigned short u16;
typedef __bf16 bf16x8 __attribute__((ext_vector_type(8)));
typedef float f32x4 __attribute__((ext_vector_type(4)));
typedef float f32x16 __attribute__((ext_vector_type(16)));
typedef float f32x4v __attribute__((ext_vector_type(4)));
typedef unsigned short u16x4 __attribute__((ext_vector_type(4)));
typedef unsigned int u32x4 __attribute__((ext_vector_type(4)));

// ---------- helpers ----------
__device__ __forceinline__ u16 f2bf(float f) {
  __bf16 h = (__bf16)f;                 // hw v_cvt (RNE)
  return __builtin_bit_cast(unsigned short, h);
}

__device__ __forceinline__ f32x16 z16() {
  f32x16 z;
#pragma unroll
  for (int i = 0; i < 16; ++i) z[i] = 0.f;
  return z;
}

// RoPE head-dim permutation: swap 16-blocks [16,32) <-> [32,48) within each
// 64-wide head. Involution. q and k permuted consistently -> QK^T unchanged.
__device__ __forceinline__ int permh(int ph) {
  int blk = ph >> 4;
  int pblk = (blk == 1) ? 2 : ((blk == 2) ? 1 : blk);
  return (pblk << 4) | (ph & 15);
}

// XOR swizzle for 128B-row LDS tiles (u16 index space), attn kernel.
__device__ __forceinline__ int SW(int r, int c) {
  return (r << 6) + (c ^ ((r & 7) << 3));
}

#define GLOAD_LDS16(gp, lp) __builtin_amdgcn_global_load_lds( \
    (const __attribute__((address_space(1))) unsigned int*)(gp), \
    (__attribute__((address_space(3))) unsigned int*)(lp), 16, 0, 0)

// raw barrier (no compiler-inserted vmcnt(0) drain) + IR memory fences
#define BAR() do { asm volatile("" ::: "memory"); __builtin_amdgcn_s_barrier(); asm volatile("" ::: "memory"); } while (0)
#define VMCNT(n) asm volatile("s_waitcnt vmcnt(" #n ")" ::: "memory")
#define LG0() asm volatile("s_waitcnt lgkmcnt(0)" ::: "memory")
#define SBAR0() __builtin_amdgcn_sched_barrier(0)

// ---------- fused prep: fp32->bf16 converts + rope tables + bias concat ----------
__global__ void prep_all(const f32x4v* __restrict__ hs, u16x4* __restrict__ hsb,
                         const f32x4v* __restrict__ wq, const f32x4v* __restrict__ wk,
                         const f32x4v* __restrict__ wv, u16x4* __restrict__ wqkvb,
                         const f32x4v* __restrict__ wo, u16x4* __restrict__ wob,
                         const int* __restrict__ pos, float* __restrict__ cosT,
                         float* __restrict__ sinT, const float* __restrict__ bq,
                         const float* __restrict__ bk, const float* __restrict__ bv,
                         float* __restrict__ bc) {
  int i = blockIdx.x * 256 + threadIdx.x;
  if (i < 2097152) {                      // hs convert (x4 units)
    f32x4v v = hs[i];
    u16x4 o; o.x = f2bf(v.x); o.y = f2bf(v.y); o.z = f2bf(v.z); o.w = f2bf(v.w);
    hsb[i] = o;
  } else if (i < 3670016) {               // Wq|Wk|Wv concat convert; Q/K rows permuted for lane-local RoPE pairs
    int j = i - 2097152;
    int row = j >> 9, c4 = j & 511;
    f32x4v v;
    if (row < 2048) {
      int sr = (row & ~63) | permh(row & 63);
      v = wq[(size_t)sr * 512 + c4];
    } else if (row < 2560) {
      int rk = row - 2048;
      int sr = (rk & ~63) | permh(rk & 63);
      v = wk[(size_t)sr * 512 + c4];
    } else {
      v = wv[(size_t)(row - 2560) * 512 + c4];
    }
    u16x4 o; o.x = f2bf(v.x); o.y = f2bf(v.y); o.z = f2bf(v.z); o.w = f2bf(v.w);
    wqkvb[j] = o;
  } else if (i < 4718592) {               // Wo convert
    int j = i - 3670016;
    f32x4v v = wo[j];
    u16x4 o; o.x = f2bf(v.x); o.y = f2bf(v.y); o.z = f2bf(v.z); o.w = f2bf(v.w);
    wob[j] = o;
  } else if (i < 4849664) {               // rope tables (4096*32)
    int j = i - 4718592;
    int bs = j >> 5, f = j & 31;
    float inv = exp2f(-(float)f * (13.287712379549449f / 32.f));
    float ang = (float)pos[bs] * inv;
    cosT[j] = cosf(ang);
    sinT[j] = sinf(ang);
  } else if (i < 4852736) {               // bias concat (3072), Q/K permuted
    int j = i - 4849664;
    float v;
    if (j < 2048) {
      v = bq[(j & ~63) | permh(j & 63)];
    } else if (j < 2560) {
      int jk = j - 2048;
      v = bk[(jk & ~63) | permh(jk & 63)];
    } else {
      v = bv[j - 2560];
    }
    bc[j] = v;
  }
}

// ---------- BMx256 8-phase GEMM (r3-proven, used for MODE 0) ----------
// 512 thr = 8 waves (2M x 4N). Phase = one (BM/2)x128 C-quadrant, snake
// order; 2 K-tiles (BK=64) per iteration, dbuf LDS. ONE barrier per phase,
// placed AFTER the MFMA cluster. Known: 66us, MfmaUtil ~30, 0 conflicts.
#define STAGE_A(kt, hh) { \
    const u16* s_ = aS + (size_t)(hh) * (BM / 2) * K + (size_t)(kt) * 64; \
    u16* d_ = lds + ((kt) & 1) * BUF + (hh) * (BM * 32) + wid * 512; \
    GLOAD_LDS16(s_, d_); \
    if constexpr (BM == 256) GLOAD_LDS16(s_ + (size_t)64 * K, d_ + 4096); \
  }

#define STAGE_B(kt, hh) { \
    const u16* s_ = bS + (size_t)(hh) * 128 * K + (size_t)(kt) * 64; \
    u16* d_ = lds + ((kt) & 1) * BUF + BM * 64 + (hh) * 8192 + wid * 512; \
    GLOAD_LDS16(s_, d_); \
    GLOAD_LDS16(s_ + (size_t)64 * K, d_ + 4096); \
  }

#define LDA8(buf, qm) { \
    const u16* p_ = lds + (buf) * BUF + ((qm) * (BM / 2) + arow) * 64; \
    _Pragma("unroll") \
    for (int mf = 0; mf < MF; ++mf) { \
      af[mf][0] = *(const bf16x8*)(p_ + mf * 1024 + koff0); \
      af[mf][1] = *(const bf16x8*)(p_ + mf * 1024 + koff1); \
    } }

#define LDB8(buf, qn) { \
    const u16* p_ = lds + (buf) * BUF + BM * 64 + ((qn) * 128 + brow) * 64; \
    _Pragma("unroll") \
    for (int nf = 0; nf < 2; ++nf) { \
      bfr[nf][0] = *(const bf16x8*)(p_ + nf * 1024 + koff0); \
      bfr[nf][1] = *(const bf16x8*)(p_ + nf * 1024 + koff1); \
    } }

#define MM8(qm, qn) { \
    __builtin_amdgcn_s_setprio(1); \
    _Pragma("unroll") \
    for (int mf = 0; mf < MF; ++mf) \
      _Pragma("unroll") \
      for (int nf = 0; nf < 2; ++nf) { \
        acc[(qm) * MF + mf][(qn) * 2 + nf] = __builtin_amdgcn_mfma_f32_16x16x32_bf16( \
            af[mf][0], bfr[nf][0], acc[(qm) * MF + mf][(qn) * 2 + nf], 0, 0, 0); \
        acc[(qm) * MF + mf][(qn) * 2 + nf] = __builtin_amdgcn_mfma_f32_16x16x32_bf16( \
            af[mf][1], bfr[nf][1], acc[(qm) * MF + mf][(qn) * 2 + nf], 0, 0, 0); \
      } \
    __builtin_amdgcn_s_setprio(0); }

#define VMCNT_GATE() do { if constexpr (BM == 256) { VMCNT(6); } else { VMCNT(4); } } while (0)

template <int MODE, int BM>
__global__ __launch_bounds__(512, 2) void gemm8(
    const u16* __restrict__ A, const u16* __restrict__ Bw, const int K, const int N,
    u16* __restrict__ qb, u16* __restrict__ kb, u16* __restrict__ vtb,
    const float* __restrict__ biasc, const float* __restrict__ cosT,
    const float* __restrict__ sinT, float* __restrict__ outf) {
  constexpr int MF = BM / 64;                   // m-frags per quadrant per wave
  constexpr int BUF = BM * 64 + 16384;          // u16 per double-buffer half
  __shared__ u16 lds[2 * BUF];                  // BM=256: 128 KiB
  const int tid = threadIdx.x;
  const int lane = tid & 63, wid = tid >> 6;
  const int wr = wid >> 2, wc = wid & 3;        // wave grid 2M x 4N
  const int col = lane & 15, rg = lane >> 4;
  const int tm = blockIdx.x, tn = blockIdx.y;

  // staging: pre-swizzled global source, linear LDS dest
  const int srow = tid >> 3;                    // 0..63
  const int scol = ((tid & 7) ^ (srow & 7)) * 8;
  const u16* aS = A + ((size_t)tm * BM + srow) * K + scol;
  const u16* bS = Bw + ((size_t)tn * 256 + srow) * K + scol;

  // swizzled ds_read offsets (u16 units); row&7 == col&7 for all frag rows
  const int koff0 = (rg ^ (col & 7)) * 8;
  const int koff1 = ((4 + rg) ^ (col & 7)) * 8;
  const int arow = wr * (BM / 4) + col;
  const int brow = wc * 32 + col;

  f32x4 acc[2 * MF][4];
#pragma unroll
  for (int i = 0; i < 2 * MF; ++i)
#pragma unroll
    for (int j = 0; j < 4; ++j) acc[i][j] = (f32x4){0.f, 0.f, 0.f, 0.f};
  bf16x8 af[MF][2], bfr[2][2];

  const int ITERS = K >> 7;             // 2 K-tiles (BK=64) per iteration

  // prologue: T0 fully, then T1.{A0,B1,A1}; T1.B0 issued at P1 of it=0
  STAGE_A(0, 0); STAGE_A(0, 1);
  STAGE_B(0, 0); STAGE_B(0, 1);
  STAGE_A(1, 0); STAGE_B(1, 1); STAGE_A(1, 1);
  VMCNT_GATE();                          // T0 landed; T1 partials in flight
  BAR();

#pragma unroll 1
  for (int it = 0; it < ITERS; ++it) {
    const int t0 = it * 2;
    const bool more = (it + 1 < ITERS);
    // P1: buf0 quadrant (0,0); stage T_{t0+1}.B0
    LDA8(0, 0); LDB8(0, 0);
    STAGE_B(t0 + 1, 0);
    MM8(0, 0); SBAR0(); BAR();
    // P2: (0,1) reuse A; stage T_{t0+2}.A0
    LDB8(0, 1);
    if (more) STAGE_A(t0 + 2, 0);
    MM8(0, 1); SBAR0(); BAR();
    // P3: (1,1) reuse B; stage T_{t0+2}.B1
    LDA8(0, 1);
    if (more) STAGE_B(t0 + 2, 1);
    MM8(1, 1); SBAR0(); BAR();
    // P4: (1,0) reuse A; stage T_{t0+2}.A1; gate buf1 reads
    LDB8(0, 0);
    if (more) STAGE_A(t0 + 2, 1);
    MM8(1, 0); SBAR0();
    if (more) { VMCNT_GATE(); } else { VMCNT(0); }
    BAR();
    // P5: buf1 quadrant (0,0); stage T_{t0+2}.B0
    LDA8(1, 0); LDB8(1, 0);
    if (more) STAGE_B(t0 + 2, 0);
    MM8(0, 0); SBAR0(); BAR();
    // P6: (0,1); stage T_{t0+3}.A0
    LDB8(1, 1);
    if (more) STAGE_A(t0 + 3, 0);
    MM8(0, 1); SBAR0(); BAR();
    // P7: (1,1); stage T_{t0+3}.B1
    LDA8(1, 1);
    if (more) STAGE_B(t0 + 3, 1);
    MM8(1, 1); SBAR0(); BAR();
    // P8: (1,0); stage T_{t0+3}.A1; gate buf0 reads
    LDB8(1, 0);
    if (more) STAGE_A(t0 + 3, 1);
    MM8(1, 0); SBAR0();
    if (more) VMCNT_GATE();
    BAR();
  }

  // epilogue (MODE 0): rows m = tm*256 + qm*128 + wr*64 + mf*16 + rg*4 + r
  //                    cols n = tn*256 + qn*128 + wc*32 + nf*16 + col
  if constexpr (MODE == 1) {
#pragma unroll
    for (int qm = 0; qm < 2; ++qm)
#pragma unroll
      for (int mf = 0; mf < MF; ++mf) {
        const int mbase = tm * BM + qm * (BM / 2) + wr * (BM / 4) + mf * 16 + rg * 4;
#pragma unroll
        for (int qn = 0; qn < 2; ++qn)
#pragma unroll
          for (int nf = 0; nf < 2; ++nf) {
            const int n = tn * 256 + qn * 128 + wc * 32 + nf * 16 + col;
#pragma unroll
            for (int r = 0; r < 4; ++r)
              outf[(size_t)(mbase + r) * N + n] = acc[qm * MF + mf][qn * 2 + nf][r];
          }
      }
  } else {
    if (tn < 8) {                       // Q heads: bias + RoPE + 0.125*log2e
      const float QS = 0.18033688011112042f;
#pragma unroll
      for (int qm = 0; qm < 2; ++qm)
#pragma unroll
        for (int qn = 0; qn < 2; ++qn) {
          const int h = tn * 4 + qn * 2 + (wc >> 1);
          const int c32 = wc & 1;
          const int n0 = tn * 256 + qn * 128 + wc * 32 + col;
          const float b1 = biasc[n0], b2 = biasc[n0 + 16];
          const int f = c32 * 16 + col;          // freq index
          const int ph0 = c32 * 32 + col;        // permuted head pos
#pragma unroll
          for (int mf = 0; mf < MF; ++mf)
#pragma unroll
            for (int r = 0; r < 4; ++r) {
              const int m = tm * 256 + qm * 128 + wr * 64 + mf * 16 + rg * 4 + r;
              const int b = m >> 11, s = m & 2047;
              const size_t base = ((size_t)(b * 32 + h) * 2048 + s) * 64;
              float x1 = acc[qm * MF + mf][qn * 2 + 0][r] + b1;
              float x2 = acc[qm * MF + mf][qn * 2 + 1][r] + b2;
              float c = cosT[m * 32 + f], sn = sinT[m * 32 + f];
              qb[base + ph0]      = f2bf((x1 * c - x2 * sn) * QS);
              qb[base + ph0 + 16] = f2bf((x2 * c + x1 * sn) * QS);
            }
        }
    } else if (tn < 10) {               // K heads
#pragma unroll
      for (int qm = 0; qm < 2; ++qm)
#pragma unroll
        for (int qn = 0; qn < 2; ++qn) {
          const int hk = (tn - 8) * 4 + qn * 2 + (wc >> 1);
          const int c32 = wc & 1;
          const int n0 = tn * 256 + qn * 128 + wc * 32 + col;
          const float b1 = biasc[n0], b2 = biasc[n0 + 16];
          const int f = c32 * 16 + col;
          const int ph0 = c32 * 32 + col;
#pragma unroll
          for (int mf = 0; mf < MF; ++mf)
#pragma unroll
            for (int r = 0; r < 4; ++r) {
              const int m = tm * 256 + qm * 128 + wr * 64 + mf * 16 + rg * 4 + r;
              const int b = m >> 11, s = m & 2047;
              const size_t base = ((size_t)(b * 8 + hk) * 2048 + s) * 64;
              float x1 = acc[qm * MF + mf][qn * 2 + 0][r] + b1;
              float x2 = acc[qm * MF + mf][qn * 2 + 1][r] + b2;
              float c = cosT[m * 32 + f], sn = sinT[m * 32 + f];
              kb[base + ph0]      = f2bf(x1 * c - x2 * sn);
              kb[base + ph0 + 16] = f2bf(x2 * c + x1 * sn);
            }
        }
    } else {                            // V heads (no rope, natural d), store [d][s]
#pragma unroll
      for (int qm = 0; qm < 2; ++qm)
#pragma unroll
        for (int qn = 0; qn < 2; ++qn)
#pragma unroll
          for (int nf = 0; nf < 2; ++nf) {
            const int n = tn * 256 + qn * 128 + wc * 32 + nf * 16 + col;
            const int hk = (n - 2560) >> 6;
            const int d = (n - 2560) & 63;
            const float bvv = biasc[n];
#pragma unroll
            for (int mf = 0; mf < MF; ++mf)
#pragma unroll
              for (int r = 0; r < 4; ++r) {
                const int m = tm * 256 + qm * 128 + wr * 64 + mf * 16 + rg * 4 + r;
                const int b = m >> 11, s = m & 2047;
                vtb[((size_t)(b * 8 + hk) * 64 + d) * 2048 + s] =
                    f2bf(acc[qm * MF + mf][qn * 2 + nf][r] + bvv);
              }
          }
    }
  }
}

// ---------- 256x128 read-ahead GEMM for O-proj (r8-proven, ~28us) ----------
#define RSTAGE_A(kt, c) GLOAD_LDS16( \
    aS + (size_t)((c) * 64) * K + (size_t)(kt) * 64, \
    lds + ((kt) & 1) * BUFSZ + (c) * 4096 + tid * 8)

#define RSTAGE_B(kt, c) GLOAD_LDS16( \
    bS + (size_t)((c) * 64) * K + (size_t)(kt) * 64, \
    lds + ((kt) & 1) * BUFSZ + 16384 + (c) * 4096 + tid * 8)

#define STAGE_H1(kt) { RSTAGE_A(kt, 0); RSTAGE_A(kt, 1); RSTAGE_A(kt, 2); }
#define STAGE_H2(kt) { RSTAGE_A(kt, 3); RSTAGE_B(kt, 0); RSTAGE_B(kt, 1); }

#define RLDA(dst, buf, kof) { \
    const u16* p_ = lds + (buf) * BUFSZ + arow * 64; \
    _Pragma("unroll") \
    for (int mf = 0; mf < 4; ++mf) dst[mf] = *(const bf16x8*)(p_ + mf * 1024 + (kof)); }

#define RLDB(dst, buf, kof) { \
    const u16* p_ = lds + (buf) * BUFSZ + 16384 + brow * 64; \
    _Pragma("unroll") \
    for (int nf = 0; nf < 4; ++nf) dst[nf] = *(const bf16x8*)(p_ + nf * 1024 + (kof)); }

#define RMM(afs, bfs) { \
    __builtin_amdgcn_s_setprio(1); \
    _Pragma("unroll") \
    for (int mf = 0; mf < 4; ++mf) \
      _Pragma("unroll") \
      for (int nf = 0; nf < 4; ++nf) \
        acc[mf][nf] = __builtin_amdgcn_mfma_f32_16x16x32_bf16(afs[mf], bfs[nf], acc[mf][nf], 0, 0, 0); \
    __builtin_amdgcn_s_setprio(0); }

__global__ void __launch_bounds__(512)
__attribute__((amdgpu_waves_per_eu(2, 2)))
gemm_o(const u16* __restrict__ A, const u16* __restrict__ Bw, const int K, const int N,
       float* __restrict__ outf) {
  constexpr int BUFSZ = (256 + 128) * 64;   // u16 per buffer (48 KiB)
  __shared__ u16 lds[2 * BUFSZ];            // 96 KiB
  const int tid = threadIdx.x;
  const int lane = tid & 63, wid = tid >> 6;
  const int wr = wid >> 1, wc = wid & 1;    // wave grid 4M x 2N
  const int col = lane & 15, rg = lane >> 4;
  const int tm = blockIdx.x, tn = blockIdx.y;

  // staging: pre-swizzled global source, linear LDS dest (64x64 chunks)
  const int srow = tid >> 3;                // 0..63
  const int scol = ((tid & 7) ^ (srow & 7)) * 8;
  const u16* aS = A + ((size_t)tm * 256 + srow) * K + scol;
  const u16* bS = Bw + ((size_t)tn * 128 + srow) * K + scol;

  // swizzled ds_read offsets (u16); row&7 == col&7 for all frag rows
  const int koff0 = (rg ^ (col & 7)) * 8;        // k-half 0
  const int koff1 = ((4 + rg) ^ (col & 7)) * 8;  // k-half 1
  const int arow = wr * 64 + col;
  const int brow = wc * 64 + col;

  f32x4 acc[4][4];
#pragma unroll
  for (int i = 0; i < 4; ++i)
#pragma unroll
    for (int j = 0; j < 4; ++j) acc[i][j] = (f32x4){0.f, 0.f, 0.f, 0.f};
  bf16x8 aX[4], aY[4], bA[4], bB[4];        // read-ahead frag double-buffer

  const int ITERS = K >> 7;                 // 2 K-tiles (BK=64) per iteration

  // prologue: stage T0+T1 fully; counted wait for T0; read P1 frags
  STAGE_H1(0); STAGE_H2(0); STAGE_H1(1); STAGE_H2(1);
  VMCNT(6);
  BAR();
  RLDA(aX, 0, koff0); RLDB(bA, 0, koff0);

#pragma unroll 1
  for (int it = 0; it < ITERS; ++it) {
    const bool more = (it + 1 < ITERS);
    // P1: MM(b0,k0); rd b0k1; finish staging tile 2it+1 (2nd half)
    if (it > 0) STAGE_H2(2 * it + 1);
    RLDA(aY, 0, koff1); RLDB(bB, 0, koff1);
    RMM(aX, bA);
    LG0(); VMCNT(0); BAR();
    // P2: MM(b0,k1); rd b1k0; stage tile 2it+2 1st half
    if (more) STAGE_H1(2 * it + 2);
    RLDA(aX, 1, koff0); RLDB(bA, 1, koff0);
    RMM(aY, bB);
    LG0(); BAR();
    // P3: MM(b1,k0); rd b1k1; stage tile 2it+2 2nd half
    if (more) STAGE_H2(2 * it + 2);
    RLDA(aY, 1, koff1); RLDB(bB, 1, koff1);
    RMM(aX, bA);
    LG0();
    if (more) VMCNT(0);
    BAR();
    // P4: MM(b1,k1); rd b0'k0; stage tile 2it+3 1st half
    if (more) {
      STAGE_H1(2 * it + 3);
      RLDA(aX, 0, koff0); RLDB(bA, 0, koff0);
    }
    RMM(aY, bB);
    LG0(); BAR();
  }

  // epilogue: m = tm*256 + wr*64 + mf*16 + rg*4 + r
  //           n = tn*128 + wc*64 + nf*16 + col
#pragma unroll
  for (int mf = 0; mf < 4; ++mf) {
    const int mbase = tm * 256 + wr * 64 + mf * 16 + rg * 4;
#pragma unroll
    for (int nf = 0; nf < 4; ++nf) {
      const int n = tn * 128 + wc * 64 + nf * 16 + col;
#pragma unroll
      for (int r = 0; r < 4; ++r)
        outf[(size_t)(mbase + r) * N + n] = acc[mf][nf][r];
    }
  }
}

// ---------- flash attention r16: paired tiles with INDEPENDENT accumulators ----------
// r15 post-mortem: barrier-halving bought 0.35us -> sync frequency isn't the
// cost. Eliminated: LDS-throughput(r5), occupancy(r11), barrier-drain(r3),
// barrier-count(r15), de-staging(r9). All pipes <35% busy -> attn is bound
// by the intra-wave DEPENDENT CHAIN (QK 4 serial MFMA -> exp2 -> pack -> PV
// 4 serial MFMA, ~700cyc), with consecutive tiles chained through the SAME
// po/l_part accumulators. Fix on the verified r15 structure: tile A and
// tile B of each pair accumulate into SEPARATE registers (poA/poB, lA/lB),
// merged once in the epilogue -> the two chains are independent dataflow
// and the scheduler interleaves them (2x latency hiding). VGPR 52->~110,
// still <128 cap at 4 blocks/CU.
#define ATTN_TILE(kv0v, Kb, Vb, p0, p1, lp) { \
      const bool diag = ((kv0v) + 32 > q0w); \
      f32x16 t = z16(); \
      _Pragma("unroll") \
      for (int s = 0; s < 4; ++s) { \
        bf16x8 kf = *(const bf16x8*)&(Kb)[SW(q32, s * 16 + hl * 8)]; \
        t = __builtin_amdgcn_mfma_f32_32x32x16_bf16(kf, qf[s], t, 0, 0, 0); \
      } \
      if (diag) { \
        const int qg = q0w + q32; \
        _Pragma("unroll") \
        for (int r = 0; r < 16; ++r) { \
          const int kvg = (kv0v) + (r & 3) + 8 * (r >> 2) + h4; \
          if (kvg > qg) t[r] = -1e30f; \
        } \
      } \
      _Pragma("unroll") \
      for (int r = 0; r < 16; ++r) t[r] = __builtin_amdgcn_exp2f(t[r]); \
      lp += (((t[0] + t[1]) + (t[2] + t[3])) + ((t[4] + t[5]) + (t[6] + t[7]))) + \
            (((t[8] + t[9]) + (t[10] + t[11])) + ((t[12] + t[13]) + (t[14] + t[15]))); \
      unsigned pw0, pw1, pw2, pw3, pw4, pw5, pw6, pw7; \
      asm("v_cvt_pk_bf16_f32 %0, %1, %2" : "=v"(pw0) : "v"(t[0]), "v"(t[1])); \
      asm("v_cvt_pk_bf16_f32 %0, %1, %2" : "=v"(pw1) : "v"(t[2]), "v"(t[3])); \
      asm("v_cvt_pk_bf16_f32 %0, %1, %2" : "=v"(pw2) : "v"(t[4]), "v"(t[5])); \
      asm("v_cvt_pk_bf16_f32 %0, %1, %2" : "=v"(pw3) : "v"(t[6]), "v"(t[7])); \
      asm("v_cvt_pk_bf16_f32 %0, %1, %2" : "=v"(pw4) : "v"(t[8]), "v"(t[9])); \
      asm("v_cvt_pk_bf16_f32 %0, %1, %2" : "=v"(pw5) : "v"(t[10]), "v"(t[11])); \
      asm("v_cvt_pk_bf16_f32 %0, %1, %2" : "=v"(pw6) : "v"(t[12]), "v"(t[13])); \
      asm("v_cvt_pk_bf16_f32 %0, %1, %2" : "=v"(pw7) : "v"(t[14]), "v"(t[15])); \
      asm("v_permlane32_swap_b32 %0, %1" : "+v"(pw0), "+v"(pw2)); \
      asm("v_permlane32_swap_b32 %0, %1" : "+v"(pw1), "+v"(pw3)); \
      asm("v_permlane32_swap_b32 %0, %1" : "+v"(pw4), "+v"(pw6)); \
      asm("v_permlane32_swap_b32 %0, %1" : "+v"(pw5), "+v"(pw7)); \
      const bf16x8 pa0 = __builtin_bit_cast(bf16x8, (u32x4){pw0, pw1, pw2, pw3}); \
      const bf16x8 pa1 = __builtin_bit_cast(bf16x8, (u32x4){pw4, pw5, pw6, pw7}); \
      _Pragma("unroll") \
      for (int dblk = 0; dblk < 2; ++dblk) { \
        const int d = dblk * 32 + q32; \
        const int vr = d >> 1, vc = (d & 1) * 32 + hl * 8; \
        bf16x8 v0 = *(const bf16x8*)&(Vb)[SW(vr, vc)]; \
        bf16x8 v1 = *(const bf16x8*)&(Vb)[SW(vr, vc + 16)]; \
        f32x16& pd = (dblk == 0) ? p0 : p1; \
        pd = __builtin_amdgcn_mfma_f32_32x32x16_bf16(pa0, v0, pd, 0, 0, 0); \
        pd = __builtin_amdgcn_mfma_f32_32x32x16_bf16(pa1, v1, pd, 0, 0, 0); \
      } \
    }

__global__ __launch_bounds__(256, 4) void attn_k(
    const u16* __restrict__ qb, const u16* __restrict__ kb,
    const u16* __restrict__ vtb, u16* __restrict__ attb) {
  __shared__ __align__(16) u16 Kl[2][2][2048];   // [slot][tile01][32 kv][64 d] swizzled
  __shared__ __align__(16) u16 Vl[2][2][2048];   // [slot][tile01] paired (d,kv) layout
  const int tid = threadIdx.x, lane = tid & 63, w = tid >> 6;  // w in 0..3
  const int q32 = lane & 31, hl = lane >> 5, h4 = hl * 4;

  const int bid = blockIdx.x;                       // 1024 blocks
  const int xcd = bid & 7, pos = bid >> 3;          // XCD-chunked
  const int grp = xcd * 8 + (pos >> 4);             // 8 (b,h) per XCD (L2-fit)
  const int s0 = pos & 15;
  const int strip = ((pos >> 5) & 1) ? (15 - s0) : s0;  // CU-complementary strips
  const int h = grp & 31, b = grp >> 5;
  const int qb0 = (15 - strip) * 128;               // longest strips at strip=0
  const int hk = h >> 2;
  const int q0w = qb0 + w * 32;                     // this wave's 32 rows

  // Q B-frags (QK^T B-operand): lane holds Q[q0w+q32][s*16 + hl*8 .. +7]
  const u16* Qp = qb + ((size_t)(b * 32 + h) * 2048 + q0w + q32) * 64 + hl * 8;
  bf16x8 qf[4];
#pragma unroll
  for (int s = 0; s < 4; ++s) qf[s] = *(const bf16x8*)(Qp + s * 16);

  // independent accumulators per pair-half: O[q=crow(r,hl)][d=dblk*32+q32]
  f32x16 poA0 = z16(), poA1 = z16(), poB0 = z16(), poB1 = z16();
  float lA = 0.f, lB = 0.f;              // softmax denom partials, q = q32

  const u16* Kbase = kb + (size_t)(b * 8 + hk) * 2048 * 64;
  const u16* Vbase = vtb + (size_t)(b * 8 + hk) * 64 * 2048;
  const int srow = tid >> 3, c8 = (tid & 7) << 3;
  const int cs = c8 ^ ((srow & 7) << 3);
  const u16* Ksrc = Kbase + (size_t)srow * 64 + cs;                         // +kv0*64/tile
  const u16* Vsrc = Vbase + (size_t)(srow * 2 + (cs >> 5)) * 2048 + (cs & 31);  // +kv0/tile
  char* Kdst0 = (char*)Kl + w * 1024;    // wave's quarter of each 4KB tile
  char* Vdst0 = (char*)Vl + w * 1024;

  const int nkv = (qb0 >> 5) + 4;        // always even (qb0 multiple of 128)
  const int npairs = nkv >> 1;
  const int rowmax = q0w + 31;

  // prologue: stage pair 0 (tiles 0,1) into slot 0
  GLOAD_LDS16(Ksrc, Kdst0);
  GLOAD_LDS16(Vsrc, Vdst0);
  GLOAD_LDS16(Ksrc + 2048, Kdst0 + 4096);
  GLOAD_LDS16(Vsrc + 32, Vdst0 + 4096);

  for (int p = 0; p < npairs; ++p) {
    const int slot = p & 1;
    if (p + 1 < npairs) {                // stage pair p+1 into slot (p+1)&1
      const int s1 = (p + 1) & 1;        // (= slot of pair p-1, retired at
      const int t0 = 2 * p + 2;          //  the end-barrier of iter p-1)
      GLOAD_LDS16(Ksrc + (size_t)t0 * 2048, Kdst0 + s1 * 8192);
      GLOAD_LDS16(Vsrc + (size_t)t0 * 32, Vdst0 + s1 * 8192);
      GLOAD_LDS16(Ksrc + (size_t)(t0 + 1) * 2048, Kdst0 + s1 * 8192 + 4096);
      GLOAD_LDS16(Vsrc + (size_t)(t0 + 1) * 32, Vdst0 + s1 * 8192 + 4096);
      VMCNT(4);                          // pair p landed (1 younger pair in flight)
    } else {
      VMCNT(0);
    }
    BAR();                               // all waves' pair-p loads landed

    const int kvA = 2 * p * 32;
    const int kvB = kvA + 32;
    const u16* KbA = &Kl[slot][0][0];
    const u16* VbA = &Vl[slot][0][0];
    const u16* KbB = &Kl[slot][1][0];
    const u16* VbB = &Vl[slot][1][0];
    __builtin_amdgcn_s_setprio(1);
    if (kvA <= rowmax) ATTN_TILE(kvA, KbA, VbA, poA0, poA1, lA);
    if (kvB <= rowmax) ATTN_TILE(kvB, KbB, VbB, poB0, poB1, lB);
    __builtin_amdgcn_s_setprio(0);

    SBAR0();
    BAR();                               // readers done; slot may be restaged
  }

  // merge pair-half accumulators, then normalize and store
  const float l_part = lA + lB;
  f32x16 po[2];
#pragma unroll
  for (int i = 0; i < 16; ++i) { po[0][i] = poA0[i] + poB0[i]; po[1][i] = poA1[i] + poB1[i]; }

  const float l_full = l_part + __shfl_xor(l_part, 32);
#pragma unroll
  for (int r = 0; r < 16; ++r) {
    const int qrl = (r & 3) + 8 * (r >> 2) + h4;      // local q row of po[.][r]
    const float lq = __shfl(l_full, qrl);             // lane qrl holds l[qrl]
    const float inv = 1.f / lq;
    const size_t base = ((size_t)b * 2048 + q0w + qrl) * 2048 + h * 64;
    attb[base + q32]      = f2bf(po[0][r] * inv);
    attb[base + 32 + q32] = f2bf(po[1][r] * inv);
  }
}

// ---------- launch ----------
extern "C" void kernel_launch(void* const* d_in, const int* in_sizes, int n_in,
                              void* d_out, int out_size, void* d_ws, size_t ws_size,
                              hipStream_t stream) {
  const float* hs = (const float*)d_in[0];
  const int* pos = (const int*)d_in[1];
  const float* Wq = (const float*)d_in[2];
  const float* bq = (const float*)d_in[3];
  const float* Wk = (const float*)d_in[4];
  const float* bk = (const float*)d_in[5];
  const float* Wv = (const float*)d_in[6];
  const float* bv = (const float*)d_in[7];
  const float* Wo = (const float*)d_in[8];
  float* out = (float*)d_out;

  char* ws = (char*)d_ws;
  size_t off = 0;
  u16* hsb = (u16*)(ws + off);   off += (size_t)4096 * 2048 * 2;
  u16* wqkvb = (u16*)(ws + off); off += (size_t)3072 * 2048 * 2;
  u16* wob = (u16*)(ws + off);   off += (size_t)2048 * 2048 * 2;
  float* biasc = (float*)(ws + off); off += 3072 * 4;
  float* cosT = (float*)(ws + off);  off += (size_t)4096 * 32 * 4;
  float* sinT = (float*)(ws + off);  off += (size_t)4096 * 32 * 4;
  u16* qb = (u16*)(ws + off);    off += (size_t)2 * 32 * 2048 * 64 * 2;
  u16* kb = (u16*)(ws + off);    off += (size_t)2 * 8 * 2048 * 64 * 2;
  u16* vtb = (u16*)(ws + off);   off += (size_t)2 * 8 * 64 * 2048 * 2;
  u16* attb = (u16*)(ws + off);  off += (size_t)4096 * 2048 * 2;

  prep_all<<<18956, 256, 0, stream>>>((const f32x4v*)hs, (u16x4*)hsb,
                                      (const f32x4v*)Wq, (const f32x4v*)Wk,
                                      (const f32x4v*)Wv, (u16x4*)wqkvb,
                                      (const f32x4v*)Wo, (u16x4*)wob,
                                      pos, cosT, sinT, bq, bk, bv, biasc);

  gemm8<0, 256><<<dim3(16, 12), 512, 0, stream>>>(hsb, wqkvb, 2048, 3072,
                                                  qb, kb, vtb, biasc, cosT, sinT, nullptr);
  attn_k<<<1024, 256, 0, stream>>>(qb, kb, vtb, attb);
  gemm_o<<<dim3(16, 16), 512, 0, stream>>>(attb, wob, 2048, 2048, out);
}

// Round 17
// 171.604 us; speedup vs baseline: 1.0871x; 1.0871x over previous
//
#include <hip/hip_runtime.h>
#include <hip/hip_bf16.h>

typedef unsigned short u16;
typedef __bf16 bf16x8 __attribute__((ext_vector_type(8)));
typedef float f32x4 __attribute__((ext_vector_type(4)));
typedef float f32x16 __attribute__((ext_vector_type(16)));
typedef float f32x4v __attribute__((ext_vector_type(4)));
typedef unsigned short u16x4 __attribute__((ext_vector_type(4)));
typedef unsigned int u32x4 __attribute__((ext_vector_type(4)));

// ---------- helpers ----------
__device__ __forceinline__ u16 f2bf(float f) {
  __bf16 h = (__bf16)f;                 // hw v_cvt (RNE)
  return __builtin_bit_cast(unsigned short, h);
}

__device__ __forceinline__ f32x16 z16() {
  f32x16 z;
#pragma unroll
  for (int i = 0; i < 16; ++i) z[i] = 0.f;
  return z;
}

// RoPE head-dim permutation: swap 16-blocks [16,32) <-> [32,48) within each
// 64-wide head. Involution. q and k permuted consistently -> QK^T unchanged.
__device__ __forceinline__ int permh(int ph) {
  int blk = ph >> 4;
  int pblk = (blk == 1) ? 2 : ((blk == 2) ? 1 : blk);
  return (pblk << 4) | (ph & 15);
}

// XOR swizzle for 128B-row LDS tiles (u16 index space), attn kernel.
__device__ __forceinline__ int SW(int r, int c) {
  return (r << 6) + (c ^ ((r & 7) << 3));
}

#define GLOAD_LDS16(gp, lp) __builtin_amdgcn_global_load_lds( \
    (const __attribute__((address_space(1))) unsigned int*)(gp), \
    (__attribute__((address_space(3))) unsigned int*)(lp), 16, 0, 0)

// raw barrier (no compiler-inserted vmcnt(0) drain) + IR memory fences
#define BAR() do { asm volatile("" ::: "memory"); __builtin_amdgcn_s_barrier(); asm volatile("" ::: "memory"); } while (0)
#define VMCNT(n) asm volatile("s_waitcnt vmcnt(" #n ")" ::: "memory")
#define LG0() asm volatile("s_waitcnt lgkmcnt(0)" ::: "memory")
#define SBAR0() __builtin_amdgcn_sched_barrier(0)

// ---------- fused prep: fp32->bf16 converts + rope tables + bias concat ----------
__global__ void prep_all(const f32x4v* __restrict__ hs, u16x4* __restrict__ hsb,
                         const f32x4v* __restrict__ wq, const f32x4v* __restrict__ wk,
                         const f32x4v* __restrict__ wv, u16x4* __restrict__ wqkvb,
                         const f32x4v* __restrict__ wo, u16x4* __restrict__ wob,
                         const int* __restrict__ pos, float* __restrict__ cosT,
                         float* __restrict__ sinT, const float* __restrict__ bq,
                         const float* __restrict__ bk, const float* __restrict__ bv,
                         float* __restrict__ bc) {
  int i = blockIdx.x * 256 + threadIdx.x;
  if (i < 2097152) {                      // hs convert (x4 units)
    f32x4v v = hs[i];
    u16x4 o; o.x = f2bf(v.x); o.y = f2bf(v.y); o.z = f2bf(v.z); o.w = f2bf(v.w);
    hsb[i] = o;
  } else if (i < 3670016) {               // Wq|Wk|Wv concat convert; Q/K rows permuted for lane-local RoPE pairs
    int j = i - 2097152;
    int row = j >> 9, c4 = j & 511;
    f32x4v v;
    if (row < 2048) {
      int sr = (row & ~63) | permh(row & 63);
      v = wq[(size_t)sr * 512 + c4];
    } else if (row < 2560) {
      int rk = row - 2048;
      int sr = (rk & ~63) | permh(rk & 63);
      v = wk[(size_t)sr * 512 + c4];
    } else {
      v = wv[(size_t)(row - 2560) * 512 + c4];
    }
    u16x4 o; o.x = f2bf(v.x); o.y = f2bf(v.y); o.z = f2bf(v.z); o.w = f2bf(v.w);
    wqkvb[j] = o;
  } else if (i < 4718592) {               // Wo convert
    int j = i - 3670016;
    f32x4v v = wo[j];
    u16x4 o; o.x = f2bf(v.x); o.y = f2bf(v.y); o.z = f2bf(v.z); o.w = f2bf(v.w);
    wob[j] = o;
  } else if (i < 4849664) {               // rope tables (4096*32)
    int j = i - 4718592;
    int bs = j >> 5, f = j & 31;
    float inv = exp2f(-(float)f * (13.287712379549449f / 32.f));
    float ang = (float)pos[bs] * inv;
    cosT[j] = cosf(ang);
    sinT[j] = sinf(ang);
  } else if (i < 4852736) {               // bias concat (3072), Q/K permuted
    int j = i - 4849664;
    float v;
    if (j < 2048) {
      v = bq[(j & ~63) | permh(j & 63)];
    } else if (j < 2560) {
      int jk = j - 2048;
      v = bk[(jk & ~63) | permh(jk & 63)];
    } else {
      v = bv[j - 2560];
    }
    bc[j] = v;
  }
}

// ---------- BMx256 8-phase GEMM (r3-proven, used for MODE 0) ----------
// 512 thr = 8 waves (2M x 4N). Phase = one (BM/2)x128 C-quadrant, snake
// order; 2 K-tiles (BK=64) per iteration, dbuf LDS. ONE barrier per phase,
// placed AFTER the MFMA cluster. Known: 66us, MfmaUtil ~30, 0 conflicts.
#define STAGE_A(kt, hh) { \
    const u16* s_ = aS + (size_t)(hh) * (BM / 2) * K + (size_t)(kt) * 64; \
    u16* d_ = lds + ((kt) & 1) * BUF + (hh) * (BM * 32) + wid * 512; \
    GLOAD_LDS16(s_, d_); \
    if constexpr (BM == 256) GLOAD_LDS16(s_ + (size_t)64 * K, d_ + 4096); \
  }

#define STAGE_B(kt, hh) { \
    const u16* s_ = bS + (size_t)(hh) * 128 * K + (size_t)(kt) * 64; \
    u16* d_ = lds + ((kt) & 1) * BUF + BM * 64 + (hh) * 8192 + wid * 512; \
    GLOAD_LDS16(s_, d_); \
    GLOAD_LDS16(s_ + (size_t)64 * K, d_ + 4096); \
  }

#define LDA8(buf, qm) { \
    const u16* p_ = lds + (buf) * BUF + ((qm) * (BM / 2) + arow) * 64; \
    _Pragma("unroll") \
    for (int mf = 0; mf < MF; ++mf) { \
      af[mf][0] = *(const bf16x8*)(p_ + mf * 1024 + koff0); \
      af[mf][1] = *(const bf16x8*)(p_ + mf * 1024 + koff1); \
    } }

#define LDB8(buf, qn) { \
    const u16* p_ = lds + (buf) * BUF + BM * 64 + ((qn) * 128 + brow) * 64; \
    _Pragma("unroll") \
    for (int nf = 0; nf < 2; ++nf) { \
      bfr[nf][0] = *(const bf16x8*)(p_ + nf * 1024 + koff0); \
      bfr[nf][1] = *(const bf16x8*)(p_ + nf * 1024 + koff1); \
    } }

#define MM8(qm, qn) { \
    __builtin_amdgcn_s_setprio(1); \
    _Pragma("unroll") \
    for (int mf = 0; mf < MF; ++mf) \
      _Pragma("unroll") \
      for (int nf = 0; nf < 2; ++nf) { \
        acc[(qm) * MF + mf][(qn) * 2 + nf] = __builtin_amdgcn_mfma_f32_16x16x32_bf16( \
            af[mf][0], bfr[nf][0], acc[(qm) * MF + mf][(qn) * 2 + nf], 0, 0, 0); \
        acc[(qm) * MF + mf][(qn) * 2 + nf] = __builtin_amdgcn_mfma_f32_16x16x32_bf16( \
            af[mf][1], bfr[nf][1], acc[(qm) * MF + mf][(qn) * 2 + nf], 0, 0, 0); \
      } \
    __builtin_amdgcn_s_setprio(0); }

#define VMCNT_GATE() do { if constexpr (BM == 256) { VMCNT(6); } else { VMCNT(4); } } while (0)

template <int MODE, int BM>
__global__ __launch_bounds__(512, 2) void gemm8(
    const u16* __restrict__ A, const u16* __restrict__ Bw, const int K, const int N,
    u16* __restrict__ qb, u16* __restrict__ kb, u16* __restrict__ vtb,
    const float* __restrict__ biasc, const float* __restrict__ cosT,
    const float* __restrict__ sinT, float* __restrict__ outf) {
  constexpr int MF = BM / 64;                   // m-frags per quadrant per wave
  constexpr int BUF = BM * 64 + 16384;          // u16 per double-buffer half
  __shared__ u16 lds[2 * BUF];                  // BM=256: 128 KiB
  const int tid = threadIdx.x;
  const int lane = tid & 63, wid = tid >> 6;
  const int wr = wid >> 2, wc = wid & 3;        // wave grid 2M x 4N
  const int col = lane & 15, rg = lane >> 4;
  const int tm = blockIdx.x, tn = blockIdx.y;

  // staging: pre-swizzled global source, linear LDS dest
  const int srow = tid >> 3;                    // 0..63
  const int scol = ((tid & 7) ^ (srow & 7)) * 8;
  const u16* aS = A + ((size_t)tm * BM + srow) * K + scol;
  const u16* bS = Bw + ((size_t)tn * 256 + srow) * K + scol;

  // swizzled ds_read offsets (u16 units); row&7 == col&7 for all frag rows
  const int koff0 = (rg ^ (col & 7)) * 8;
  const int koff1 = ((4 + rg) ^ (col & 7)) * 8;
  const int arow = wr * (BM / 4) + col;
  const int brow = wc * 32 + col;

  f32x4 acc[2 * MF][4];
#pragma unroll
  for (int i = 0; i < 2 * MF; ++i)
#pragma unroll
    for (int j = 0; j < 4; ++j) acc[i][j] = (f32x4){0.f, 0.f, 0.f, 0.f};
  bf16x8 af[MF][2], bfr[2][2];

  const int ITERS = K >> 7;             // 2 K-tiles (BK=64) per iteration

  // prologue: T0 fully, then T1.{A0,B1,A1}; T1.B0 issued at P1 of it=0
  STAGE_A(0, 0); STAGE_A(0, 1);
  STAGE_B(0, 0); STAGE_B(0, 1);
  STAGE_A(1, 0); STAGE_B(1, 1); STAGE_A(1, 1);
  VMCNT_GATE();                          // T0 landed; T1 partials in flight
  BAR();

#pragma unroll 1
  for (int it = 0; it < ITERS; ++it) {
    const int t0 = it * 2;
    const bool more = (it + 1 < ITERS);
    // P1: buf0 quadrant (0,0); stage T_{t0+1}.B0
    LDA8(0, 0); LDB8(0, 0);
    STAGE_B(t0 + 1, 0);
    MM8(0, 0); SBAR0(); BAR();
    // P2: (0,1) reuse A; stage T_{t0+2}.A0
    LDB8(0, 1);
    if (more) STAGE_A(t0 + 2, 0);
    MM8(0, 1); SBAR0(); BAR();
    // P3: (1,1) reuse B; stage T_{t0+2}.B1
    LDA8(0, 1);
    if (more) STAGE_B(t0 + 2, 1);
    MM8(1, 1); SBAR0(); BAR();
    // P4: (1,0) reuse A; stage T_{t0+2}.A1; gate buf1 reads
    LDB8(0, 0);
    if (more) STAGE_A(t0 + 2, 1);
    MM8(1, 0); SBAR0();
    if (more) { VMCNT_GATE(); } else { VMCNT(0); }
    BAR();
    // P5: buf1 quadrant (0,0); stage T_{t0+2}.B0
    LDA8(1, 0); LDB8(1, 0);
    if (more) STAGE_B(t0 + 2, 0);
    MM8(0, 0); SBAR0(); BAR();
    // P6: (0,1); stage T_{t0+3}.A0
    LDB8(1, 1);
    if (more) STAGE_A(t0 + 3, 0);
    MM8(0, 1); SBAR0(); BAR();
    // P7: (1,1); stage T_{t0+3}.B1
    LDA8(1, 1);
    if (more) STAGE_B(t0 + 3, 1);
    MM8(1, 1); SBAR0(); BAR();
    // P8: (1,0); stage T_{t0+3}.A1; gate buf0 reads
    LDB8(1, 0);
    if (more) STAGE_A(t0 + 3, 1);
    MM8(1, 0); SBAR0();
    if (more) VMCNT_GATE();
    BAR();
  }

  // epilogue (MODE 0): rows m = tm*256 + qm*128 + wr*64 + mf*16 + rg*4 + r
  //                    cols n = tn*256 + qn*128 + wc*32 + nf*16 + col
  if constexpr (MODE == 1) {
#pragma unroll
    for (int qm = 0; qm < 2; ++qm)
#pragma unroll
      for (int mf = 0; mf < MF; ++mf) {
        const int mbase = tm * BM + qm * (BM / 2) + wr * (BM / 4) + mf * 16 + rg * 4;
#pragma unroll
        for (int qn = 0; qn < 2; ++qn)
#pragma unroll
          for (int nf = 0; nf < 2; ++nf) {
            const int n = tn * 256 + qn * 128 + wc * 32 + nf * 16 + col;
#pragma unroll
            for (int r = 0; r < 4; ++r)
              outf[(size_t)(mbase + r) * N + n] = acc[qm * MF + mf][qn * 2 + nf][r];
          }
      }
  } else {
    if (tn < 8) {                       // Q heads: bias + RoPE + 0.125*log2e
      const float QS = 0.18033688011112042f;
#pragma unroll
      for (int qm = 0; qm < 2; ++qm)
#pragma unroll
        for (int qn = 0; qn < 2; ++qn) {
          const int h = tn * 4 + qn * 2 + (wc >> 1);
          const int c32 = wc & 1;
          const int n0 = tn * 256 + qn * 128 + wc * 32 + col;
          const float b1 = biasc[n0], b2 = biasc[n0 + 16];
          const int f = c32 * 16 + col;          // freq index
          const int ph0 = c32 * 32 + col;        // permuted head pos
#pragma unroll
          for (int mf = 0; mf < MF; ++mf)
#pragma unroll
            for (int r = 0; r < 4; ++r) {
              const int m = tm * 256 + qm * 128 + wr * 64 + mf * 16 + rg * 4 + r;
              const int b = m >> 11, s = m & 2047;
              const size_t base = ((size_t)(b * 32 + h) * 2048 + s) * 64;
              float x1 = acc[qm * MF + mf][qn * 2 + 0][r] + b1;
              float x2 = acc[qm * MF + mf][qn * 2 + 1][r] + b2;
              float c = cosT[m * 32 + f], sn = sinT[m * 32 + f];
              qb[base + ph0]      = f2bf((x1 * c - x2 * sn) * QS);
              qb[base + ph0 + 16] = f2bf((x2 * c + x1 * sn) * QS);
            }
        }
    } else if (tn < 10) {               // K heads
#pragma unroll
      for (int qm = 0; qm < 2; ++qm)
#pragma unroll
        for (int qn = 0; qn < 2; ++qn) {
          const int hk = (tn - 8) * 4 + qn * 2 + (wc >> 1);
          const int c32 = wc & 1;
          const int n0 = tn * 256 + qn * 128 + wc * 32 + col;
          const float b1 = biasc[n0], b2 = biasc[n0 + 16];
          const int f = c32 * 16 + col;
          const int ph0 = c32 * 32 + col;
#pragma unroll
          for (int mf = 0; mf < MF; ++mf)
#pragma unroll
            for (int r = 0; r < 4; ++r) {
              const int m = tm * 256 + qm * 128 + wr * 64 + mf * 16 + rg * 4 + r;
              const int b = m >> 11, s = m & 2047;
              const size_t base = ((size_t)(b * 8 + hk) * 2048 + s) * 64;
              float x1 = acc[qm * MF + mf][qn * 2 + 0][r] + b1;
              float x2 = acc[qm * MF + mf][qn * 2 + 1][r] + b2;
              float c = cosT[m * 32 + f], sn = sinT[m * 32 + f];
              kb[base + ph0]      = f2bf(x1 * c - x2 * sn);
              kb[base + ph0 + 16] = f2bf(x2 * c + x1 * sn);
            }
        }
    } else {                            // V heads (no rope, natural d), store [d][s]
#pragma unroll
      for (int qm = 0; qm < 2; ++qm)
#pragma unroll
        for (int qn = 0; qn < 2; ++qn)
#pragma unroll
          for (int nf = 0; nf < 2; ++nf) {
            const int n = tn * 256 + qn * 128 + wc * 32 + nf * 16 + col;
            const int hk = (n - 2560) >> 6;
            const int d = (n - 2560) & 63;
            const float bvv = biasc[n];
#pragma unroll
            for (int mf = 0; mf < MF; ++mf)
#pragma unroll
              for (int r = 0; r < 4; ++r) {
                const int m = tm * 256 + qm * 128 + wr * 64 + mf * 16 + rg * 4 + r;
                const int b = m >> 11, s = m & 2047;
                vtb[((size_t)(b * 8 + hk) * 64 + d) * 2048 + s] =
                    f2bf(acc[qm * MF + mf][qn * 2 + nf][r] + bvv);
              }
          }
    }
  }
}

// ---------- 256x128 read-ahead GEMM for O-proj (r8-proven, ~28us) ----------
#define RSTAGE_A(kt, c) GLOAD_LDS16( \
    aS + (size_t)((c) * 64) * K + (size_t)(kt) * 64, \
    lds + ((kt) & 1) * BUFSZ + (c) * 4096 + tid * 8)

#define RSTAGE_B(kt, c) GLOAD_LDS16( \
    bS + (size_t)((c) * 64) * K + (size_t)(kt) * 64, \
    lds + ((kt) & 1) * BUFSZ + 16384 + (c) * 4096 + tid * 8)

#define STAGE_H1(kt) { RSTAGE_A(kt, 0); RSTAGE_A(kt, 1); RSTAGE_A(kt, 2); }
#define STAGE_H2(kt) { RSTAGE_A(kt, 3); RSTAGE_B(kt, 0); RSTAGE_B(kt, 1); }

#define RLDA(dst, buf, kof) { \
    const u16* p_ = lds + (buf) * BUFSZ + arow * 64; \
    _Pragma("unroll") \
    for (int mf = 0; mf < 4; ++mf) dst[mf] = *(const bf16x8*)(p_ + mf * 1024 + (kof)); }

#define RLDB(dst, buf, kof) { \
    const u16* p_ = lds + (buf) * BUFSZ + 16384 + brow * 64; \
    _Pragma("unroll") \
    for (int nf = 0; nf < 4; ++nf) dst[nf] = *(const bf16x8*)(p_ + nf * 1024 + (kof)); }

#define RMM(afs, bfs) { \
    __builtin_amdgcn_s_setprio(1); \
    _Pragma("unroll") \
    for (int mf = 0; mf < 4; ++mf) \
      _Pragma("unroll") \
      for (int nf = 0; nf < 4; ++nf) \
        acc[mf][nf] = __builtin_amdgcn_mfma_f32_16x16x32_bf16(afs[mf], bfs[nf], acc[mf][nf], 0, 0, 0); \
    __builtin_amdgcn_s_setprio(0); }

__global__ void __launch_bounds__(512)
__attribute__((amdgpu_waves_per_eu(2, 2)))
gemm_o(const u16* __restrict__ A, const u16* __restrict__ Bw, const int K, const int N,
       float* __restrict__ outf) {
  constexpr int BUFSZ = (256 + 128) * 64;   // u16 per buffer (48 KiB)
  __shared__ u16 lds[2 * BUFSZ];            // 96 KiB
  const int tid = threadIdx.x;
  const int lane = tid & 63, wid = tid >> 6;
  const int wr = wid >> 1, wc = wid & 1;    // wave grid 4M x 2N
  const int col = lane & 15, rg = lane >> 4;
  const int tm = blockIdx.x, tn = blockIdx.y;

  // staging: pre-swizzled global source, linear LDS dest (64x64 chunks)
  const int srow = tid >> 3;                // 0..63
  const int scol = ((tid & 7) ^ (srow & 7)) * 8;
  const u16* aS = A + ((size_t)tm * 256 + srow) * K + scol;
  const u16* bS = Bw + ((size_t)tn * 128 + srow) * K + scol;

  // swizzled ds_read offsets (u16); row&7 == col&7 for all frag rows
  const int koff0 = (rg ^ (col & 7)) * 8;        // k-half 0
  const int koff1 = ((4 + rg) ^ (col & 7)) * 8;  // k-half 1
  const int arow = wr * 64 + col;
  const int brow = wc * 64 + col;

  f32x4 acc[4][4];
#pragma unroll
  for (int i = 0; i < 4; ++i)
#pragma unroll
    for (int j = 0; j < 4; ++j) acc[i][j] = (f32x4){0.f, 0.f, 0.f, 0.f};
  bf16x8 aX[4], aY[4], bA[4], bB[4];        // read-ahead frag double-buffer

  const int ITERS = K >> 7;                 // 2 K-tiles (BK=64) per iteration

  // prologue: stage T0+T1 fully; counted wait for T0; read P1 frags
  STAGE_H1(0); STAGE_H2(0); STAGE_H1(1); STAGE_H2(1);
  VMCNT(6);
  BAR();
  RLDA(aX, 0, koff0); RLDB(bA, 0, koff0);

#pragma unroll 1
  for (int it = 0; it < ITERS; ++it) {
    const bool more = (it + 1 < ITERS);
    // P1: MM(b0,k0); rd b0k1; finish staging tile 2it+1 (2nd half)
    if (it > 0) STAGE_H2(2 * it + 1);
    RLDA(aY, 0, koff1); RLDB(bB, 0, koff1);
    RMM(aX, bA);
    LG0(); VMCNT(0); BAR();
    // P2: MM(b0,k1); rd b1k0; stage tile 2it+2 1st half
    if (more) STAGE_H1(2 * it + 2);
    RLDA(aX, 1, koff0); RLDB(bA, 1, koff0);
    RMM(aY, bB);
    LG0(); BAR();
    // P3: MM(b1,k0); rd b1k1; stage tile 2it+2 2nd half
    if (more) STAGE_H2(2 * it + 2);
    RLDA(aY, 1, koff1); RLDB(bB, 1, koff1);
    RMM(aX, bA);
    LG0();
    if (more) VMCNT(0);
    BAR();
    // P4: MM(b1,k1); rd b0'k0; stage tile 2it+3 1st half
    if (more) {
      STAGE_H1(2 * it + 3);
      RLDA(aX, 0, koff0); RLDB(bA, 0, koff0);
    }
    RMM(aY, bB);
    LG0(); BAR();
  }

  // epilogue: m = tm*256 + wr*64 + mf*16 + rg*4 + r
  //           n = tn*128 + wc*64 + nf*16 + col
#pragma unroll
  for (int mf = 0; mf < 4; ++mf) {
    const int mbase = tm * 256 + wr * 64 + mf * 16 + rg * 4;
#pragma unroll
    for (int nf = 0; nf < 4; ++nf) {
      const int n = tn * 128 + wc * 64 + nf * 16 + col;
#pragma unroll
      for (int r = 0; r < 4; ++r)
        outf[(size_t)(mbase + r) * N + n] = acc[mf][nf][r];
    }
  }
}

// ---------- flash attention (r15-proven): TWO 32-kv tiles per barrier pair ----------
// Best-measured attn variant (~65.5us within the 171.7 total). Shared
// accumulators (r16's split-accumulator variant spilled at the 128-VGPR cap
// and regressed to 86us). 32x32x16 MFMAs, P fully in-register
// (cvt_pk + v_permlane32_swap_b32), paired staging with counted vmcnt.
#define ATTN_TILE(kv0v, Kb, Vb) { \
      const bool diag = ((kv0v) + 32 > q0w); \
      f32x16 t = z16(); \
      _Pragma("unroll") \
      for (int s = 0; s < 4; ++s) { \
        bf16x8 kf = *(const bf16x8*)&(Kb)[SW(q32, s * 16 + hl * 8)]; \
        t = __builtin_amdgcn_mfma_f32_32x32x16_bf16(kf, qf[s], t, 0, 0, 0); \
      } \
      if (diag) { \
        const int qg = q0w + q32; \
        _Pragma("unroll") \
        for (int r = 0; r < 16; ++r) { \
          const int kvg = (kv0v) + (r & 3) + 8 * (r >> 2) + h4; \
          if (kvg > qg) t[r] = -1e30f; \
        } \
      } \
      _Pragma("unroll") \
      for (int r = 0; r < 16; ++r) t[r] = __builtin_amdgcn_exp2f(t[r]); \
      l_part += (((t[0] + t[1]) + (t[2] + t[3])) + ((t[4] + t[5]) + (t[6] + t[7]))) + \
                (((t[8] + t[9]) + (t[10] + t[11])) + ((t[12] + t[13]) + (t[14] + t[15]))); \
      unsigned pw0, pw1, pw2, pw3, pw4, pw5, pw6, pw7; \
      asm("v_cvt_pk_bf16_f32 %0, %1, %2" : "=v"(pw0) : "v"(t[0]), "v"(t[1])); \
      asm("v_cvt_pk_bf16_f32 %0, %1, %2" : "=v"(pw1) : "v"(t[2]), "v"(t[3])); \
      asm("v_cvt_pk_bf16_f32 %0, %1, %2" : "=v"(pw2) : "v"(t[4]), "v"(t[5])); \
      asm("v_cvt_pk_bf16_f32 %0, %1, %2" : "=v"(pw3) : "v"(t[6]), "v"(t[7])); \
      asm("v_cvt_pk_bf16_f32 %0, %1, %2" : "=v"(pw4) : "v"(t[8]), "v"(t[9])); \
      asm("v_cvt_pk_bf16_f32 %0, %1, %2" : "=v"(pw5) : "v"(t[10]), "v"(t[11])); \
      asm("v_cvt_pk_bf16_f32 %0, %1, %2" : "=v"(pw6) : "v"(t[12]), "v"(t[13])); \
      asm("v_cvt_pk_bf16_f32 %0, %1, %2" : "=v"(pw7) : "v"(t[14]), "v"(t[15])); \
      asm("v_permlane32_swap_b32 %0, %1" : "+v"(pw0), "+v"(pw2)); \
      asm("v_permlane32_swap_b32 %0, %1" : "+v"(pw1), "+v"(pw3)); \
      asm("v_permlane32_swap_b32 %0, %1" : "+v"(pw4), "+v"(pw6)); \
      asm("v_permlane32_swap_b32 %0, %1" : "+v"(pw5), "+v"(pw7)); \
      const bf16x8 pa0 = __builtin_bit_cast(bf16x8, (u32x4){pw0, pw1, pw2, pw3}); \
      const bf16x8 pa1 = __builtin_bit_cast(bf16x8, (u32x4){pw4, pw5, pw6, pw7}); \
      __builtin_amdgcn_s_setprio(1); \
      _Pragma("unroll") \
      for (int dblk = 0; dblk < 2; ++dblk) { \
        const int d = dblk * 32 + q32; \
        const int vr = d >> 1, vc = (d & 1) * 32 + hl * 8; \
        bf16x8 v0 = *(const bf16x8*)&(Vb)[SW(vr, vc)]; \
        bf16x8 v1 = *(const bf16x8*)&(Vb)[SW(vr, vc + 16)]; \
        po[dblk] = __builtin_amdgcn_mfma_f32_32x32x16_bf16(pa0, v0, po[dblk], 0, 0, 0); \
        po[dblk] = __builtin_amdgcn_mfma_f32_32x32x16_bf16(pa1, v1, po[dblk], 0, 0, 0); \
      } \
      __builtin_amdgcn_s_setprio(0); \
    }

__global__ __launch_bounds__(256, 4) void attn_k(
    const u16* __restrict__ qb, const u16* __restrict__ kb,
    const u16* __restrict__ vtb, u16* __restrict__ attb) {
  __shared__ __align__(16) u16 Kl[2][2][2048];   // [slot][tile01][32 kv][64 d] swizzled
  __shared__ __align__(16) u16 Vl[2][2][2048];   // [slot][tile01] paired (d,kv) layout
  const int tid = threadIdx.x, lane = tid & 63, w = tid >> 6;  // w in 0..3
  const int q32 = lane & 31, hl = lane >> 5, h4 = hl * 4;

  const int bid = blockIdx.x;                       // 1024 blocks
  const int xcd = bid & 7, pos = bid >> 3;          // XCD-chunked
  const int grp = xcd * 8 + (pos >> 4);             // 8 (b,h) per XCD (L2-fit)
  const int s0 = pos & 15;
  const int strip = ((pos >> 5) & 1) ? (15 - s0) : s0;  // CU-complementary strips
  const int h = grp & 31, b = grp >> 5;
  const int qb0 = (15 - strip) * 128;               // longest strips at strip=0
  const int hk = h >> 2;
  const int q0w = qb0 + w * 32;                     // this wave's 32 rows

  // Q B-frags (QK^T B-operand): lane holds Q[q0w+q32][s*16 + hl*8 .. +7]
  const u16* Qp = qb + ((size_t)(b * 32 + h) * 2048 + q0w + q32) * 64 + hl * 8;
  bf16x8 qf[4];
#pragma unroll
  for (int s = 0; s < 4; ++s) qf[s] = *(const bf16x8*)(Qp + s * 16);

  f32x16 po[2];                          // O[q=crow(r,hl)][d=dblk*32+q32]
  po[0] = z16(); po[1] = z16();
  float l_part = 0.f;                    // softmax denom partial, q = q32

  const u16* Kbase = kb + (size_t)(b * 8 + hk) * 2048 * 64;
  const u16* Vbase = vtb + (size_t)(b * 8 + hk) * 64 * 2048;
  const int srow = tid >> 3, c8 = (tid & 7) << 3;
  const int cs = c8 ^ ((srow & 7) << 3);
  const u16* Ksrc = Kbase + (size_t)srow * 64 + cs;                         // +kv0*64/tile
  const u16* Vsrc = Vbase + (size_t)(srow * 2 + (cs >> 5)) * 2048 + (cs & 31);  // +kv0/tile
  char* Kdst0 = (char*)Kl + w * 1024;    // wave's quarter of each 4KB tile
  char* Vdst0 = (char*)Vl + w * 1024;

  const int nkv = (qb0 >> 5) + 4;        // always even (qb0 multiple of 128)
  const int npairs = nkv >> 1;
  const int rowmax = q0w + 31;

  // prologue: stage pair 0 (tiles 0,1) into slot 0
  GLOAD_LDS16(Ksrc, Kdst0);
  GLOAD_LDS16(Vsrc, Vdst0);
  GLOAD_LDS16(Ksrc + 2048, Kdst0 + 4096);
  GLOAD_LDS16(Vsrc + 32, Vdst0 + 4096);

  for (int p = 0; p < npairs; ++p) {
    const int slot = p & 1;
    if (p + 1 < npairs) {                // stage pair p+1 into slot (p+1)&1
      const int s1 = (p + 1) & 1;        // (= slot of pair p-1, retired at
      const int t0 = 2 * p + 2;          //  the end-barrier of iter p-1)
      GLOAD_LDS16(Ksrc + (size_t)t0 * 2048, Kdst0 + s1 * 8192);
      GLOAD_LDS16(Vsrc + (size_t)t0 * 32, Vdst0 + s1 * 8192);
      GLOAD_LDS16(Ksrc + (size_t)(t0 + 1) * 2048, Kdst0 + s1 * 8192 + 4096);
      GLOAD_LDS16(Vsrc + (size_t)(t0 + 1) * 32, Vdst0 + s1 * 8192 + 4096);
      VMCNT(4);                          // pair p landed (1 younger pair in flight)
    } else {
      VMCNT(0);
    }
    BAR();                               // all waves' pair-p loads landed

    const int kvA = 2 * p * 32;
    const int kvB = kvA + 32;
    const u16* KbA = &Kl[slot][0][0];
    const u16* VbA = &Vl[slot][0][0];
    if (kvA <= rowmax) ATTN_TILE(kvA, KbA, VbA);
    const u16* KbB = &Kl[slot][1][0];
    const u16* VbB = &Vl[slot][1][0];
    if (kvB <= rowmax) ATTN_TILE(kvB, KbB, VbB);

    SBAR0();
    BAR();                               // readers done; slot may be restaged
  }

  // epilogue: l_full(lane) = denom for q=q32 (partner half holds other kv)
  const float l_full = l_part + __shfl_xor(l_part, 32);
#pragma unroll
  for (int r = 0; r < 16; ++r) {
    const int qrl = (r & 3) + 8 * (r >> 2) + h4;      // local q row of po[.][r]
    const float lq = __shfl(l_full, qrl);             // lane qrl holds l[qrl]
    const float inv = 1.f / lq;
    const size_t base = ((size_t)b * 2048 + q0w + qrl) * 2048 + h * 64;
    attb[base + q32]      = f2bf(po[0][r] * inv);
    attb[base + 32 + q32] = f2bf(po[1][r] * inv);
  }
}

// ---------- launch ----------
extern "C" void kernel_launch(void* const* d_in, const int* in_sizes, int n_in,
                              void* d_out, int out_size, void* d_ws, size_t ws_size,
                              hipStream_t stream) {
  const float* hs = (const float*)d_in[0];
  const int* pos = (const int*)d_in[1];
  const float* Wq = (const float*)d_in[2];
  const float* bq = (const float*)d_in[3];
  const float* Wk = (const float*)d_in[4];
  const float* bk = (const float*)d_in[5];
  const float* Wv = (const float*)d_in[6];
  const float* bv = (const float*)d_in[7];
  const float* Wo = (const float*)d_in[8];
  float* out = (float*)d_out;

  char* ws = (char*)d_ws;
  size_t off = 0;
  u16* hsb = (u16*)(ws + off);   off += (size_t)4096 * 2048 * 2;
  u16* wqkvb = (u16*)(ws + off); off += (size_t)3072 * 2048 * 2;
  u16* wob = (u16*)(ws + off);   off += (size_t)2048 * 2048 * 2;
  float* biasc = (float*)(ws + off); off += 3072 * 4;
  float* cosT = (float*)(ws + off);  off += (size_t)4096 * 32 * 4;
  float* sinT = (float*)(ws + off);  off += (size_t)4096 * 32 * 4;
  u16* qb = (u16*)(ws + off);    off += (size_t)2 * 32 * 2048 * 64 * 2;
  u16* kb = (u16*)(ws + off);    off += (size_t)2 * 8 * 2048 * 64 * 2;
  u16* vtb = (u16*)(ws + off);   off += (size_t)2 * 8 * 64 * 2048 * 2;
  u16* attb = (u16*)(ws + off);  off += (size_t)4096 * 2048 * 2;

  prep_all<<<18956, 256, 0, stream>>>((const f32x4v*)hs, (u16x4*)hsb,
                                      (const f32x4v*)Wq, (const f32x4v*)Wk,
                                      (const f32x4v*)Wv, (u16x4*)wqkvb,
                                      (const f32x4v*)Wo, (u16x4*)wob,
                                      pos, cosT, sinT, bq, bk, bv, biasc);

  gemm8<0, 256><<<dim3(16, 12), 512, 0, stream>>>(hsb, wqkvb, 2048, 3072,
                                                  qb, kb, vtb, biasc, cosT, sinT, nullptr);
  attn_k<<<1024, 256, 0, stream>>>(qb, kb, vtb, attb);
  gemm_o<<<dim3(16, 16), 512, 0, stream>>>(attb, wob, 2048, 2048, out);
}

// Round 18
// 169.540 us; speedup vs baseline: 1.1003x; 1.0122x over previous
//
#include <hip/hip_runtime.h>
#include <hip/hip_bf16.h>

typedef unsigned short u16;
typedef __bf16 bf16x8 __attribute__((ext_vector_type(8)));
typedef float f32x4 __attribute__((ext_vector_type(4)));
typedef float f32x16 __attribute__((ext_vector_type(16)));
typedef float f32x4v __attribute__((ext_vector_type(4)));
typedef unsigned short u16x4 __attribute__((ext_vector_type(4)));
typedef unsigned int u32x4 __attribute__((ext_vector_type(4)));

// ---------- helpers ----------
__device__ __forceinline__ u16 f2bf(float f) {
  __bf16 h = (__bf16)f;                 // hw v_cvt (RNE)
  return __builtin_bit_cast(unsigned short, h);
}

__device__ __forceinline__ f32x16 z16() {
  f32x16 z;
#pragma unroll
  for (int i = 0; i < 16; ++i) z[i] = 0.f;
  return z;
}

// RoPE head-dim permutation: swap 16-blocks [16,32) <-> [32,48) within each
// 64-wide head. Involution. q and k permuted consistently -> QK^T unchanged.
__device__ __forceinline__ int permh(int ph) {
  int blk = ph >> 4;
  int pblk = (blk == 1) ? 2 : ((blk == 2) ? 1 : blk);
  return (pblk << 4) | (ph & 15);
}

// XOR swizzle for 128B-row LDS tiles (u16 index space), attn kernel.
__device__ __forceinline__ int SW(int r, int c) {
  return (r << 6) + (c ^ ((r & 7) << 3));
}

#define GLOAD_LDS16(gp, lp) __builtin_amdgcn_global_load_lds( \
    (const __attribute__((address_space(1))) unsigned int*)(gp), \
    (__attribute__((address_space(3))) unsigned int*)(lp), 16, 0, 0)

// raw barrier (no compiler-inserted vmcnt(0) drain) + IR memory fences
#define BAR() do { asm volatile("" ::: "memory"); __builtin_amdgcn_s_barrier(); asm volatile("" ::: "memory"); } while (0)
#define VMCNT(n) asm volatile("s_waitcnt vmcnt(" #n ")" ::: "memory")
#define LG0() asm volatile("s_waitcnt lgkmcnt(0)" ::: "memory")
#define SBAR0() __builtin_amdgcn_sched_barrier(0)

// ---------- fused prep: fp32->bf16 converts + rope tables + bias concat ----------
__global__ void prep_all(const f32x4v* __restrict__ hs, u16x4* __restrict__ hsb,
                         const f32x4v* __restrict__ wq, const f32x4v* __restrict__ wk,
                         const f32x4v* __restrict__ wv, u16x4* __restrict__ wqkvb,
                         const f32x4v* __restrict__ wo, u16x4* __restrict__ wob,
                         const int* __restrict__ pos, float* __restrict__ cosT,
                         float* __restrict__ sinT, const float* __restrict__ bq,
                         const float* __restrict__ bk, const float* __restrict__ bv,
                         float* __restrict__ bc) {
  int i = blockIdx.x * 256 + threadIdx.x;
  if (i < 2097152) {                      // hs convert (x4 units)
    f32x4v v = hs[i];
    u16x4 o; o.x = f2bf(v.x); o.y = f2bf(v.y); o.z = f2bf(v.z); o.w = f2bf(v.w);
    hsb[i] = o;
  } else if (i < 3670016) {               // Wq|Wk|Wv concat convert; Q/K rows permuted for lane-local RoPE pairs
    int j = i - 2097152;
    int row = j >> 9, c4 = j & 511;
    f32x4v v;
    if (row < 2048) {
      int sr = (row & ~63) | permh(row & 63);
      v = wq[(size_t)sr * 512 + c4];
    } else if (row < 2560) {
      int rk = row - 2048;
      int sr = (rk & ~63) | permh(rk & 63);
      v = wk[(size_t)sr * 512 + c4];
    } else {
      v = wv[(size_t)(row - 2560) * 512 + c4];
    }
    u16x4 o; o.x = f2bf(v.x); o.y = f2bf(v.y); o.z = f2bf(v.z); o.w = f2bf(v.w);
    wqkvb[j] = o;
  } else if (i < 4718592) {               // Wo convert
    int j = i - 3670016;
    f32x4v v = wo[j];
    u16x4 o; o.x = f2bf(v.x); o.y = f2bf(v.y); o.z = f2bf(v.z); o.w = f2bf(v.w);
    wob[j] = o;
  } else if (i < 4849664) {               // rope tables (4096*32)
    int j = i - 4718592;
    int bs = j >> 5, f = j & 31;
    float inv = exp2f(-(float)f * (13.287712379549449f / 32.f));
    float ang = (float)pos[bs] * inv;
    cosT[j] = cosf(ang);
    sinT[j] = sinf(ang);
  } else if (i < 4852736) {               // bias concat (3072), Q/K permuted
    int j = i - 4849664;
    float v;
    if (j < 2048) {
      v = bq[(j & ~63) | permh(j & 63)];
    } else if (j < 2560) {
      int jk = j - 2048;
      v = bk[(jk & ~63) | permh(jk & 63)];
    } else {
      v = bv[j - 2560];
    }
    bc[j] = v;
  }
}

// ---------- BMx256 8-phase GEMM (r3-proven, used for MODE 0) ----------
// 512 thr = 8 waves (2M x 4N). Phase = one (BM/2)x128 C-quadrant, snake
// order; 2 K-tiles (BK=64) per iteration, dbuf LDS. ONE barrier per phase,
// placed AFTER the MFMA cluster. Known: 66us, MfmaUtil ~30, 0 conflicts.
#define STAGE_A(kt, hh) { \
    const u16* s_ = aS + (size_t)(hh) * (BM / 2) * K + (size_t)(kt) * 64; \
    u16* d_ = lds + ((kt) & 1) * BUF + (hh) * (BM * 32) + wid * 512; \
    GLOAD_LDS16(s_, d_); \
    if constexpr (BM == 256) GLOAD_LDS16(s_ + (size_t)64 * K, d_ + 4096); \
  }

#define STAGE_B(kt, hh) { \
    const u16* s_ = bS + (size_t)(hh) * 128 * K + (size_t)(kt) * 64; \
    u16* d_ = lds + ((kt) & 1) * BUF + BM * 64 + (hh) * 8192 + wid * 512; \
    GLOAD_LDS16(s_, d_); \
    GLOAD_LDS16(s_ + (size_t)64 * K, d_ + 4096); \
  }

#define LDA8(buf, qm) { \
    const u16* p_ = lds + (buf) * BUF + ((qm) * (BM / 2) + arow) * 64; \
    _Pragma("unroll") \
    for (int mf = 0; mf < MF; ++mf) { \
      af[mf][0] = *(const bf16x8*)(p_ + mf * 1024 + koff0); \
      af[mf][1] = *(const bf16x8*)(p_ + mf * 1024 + koff1); \
    } }

#define LDB8(buf, qn) { \
    const u16* p_ = lds + (buf) * BUF + BM * 64 + ((qn) * 128 + brow) * 64; \
    _Pragma("unroll") \
    for (int nf = 0; nf < 2; ++nf) { \
      bfr[nf][0] = *(const bf16x8*)(p_ + nf * 1024 + koff0); \
      bfr[nf][1] = *(const bf16x8*)(p_ + nf * 1024 + koff1); \
    } }

#define MM8(qm, qn) { \
    __builtin_amdgcn_s_setprio(1); \
    _Pragma("unroll") \
    for (int mf = 0; mf < MF; ++mf) \
      _Pragma("unroll") \
      for (int nf = 0; nf < 2; ++nf) { \
        acc[(qm) * MF + mf][(qn) * 2 + nf] = __builtin_amdgcn_mfma_f32_16x16x32_bf16( \
            af[mf][0], bfr[nf][0], acc[(qm) * MF + mf][(qn) * 2 + nf], 0, 0, 0); \
        acc[(qm) * MF + mf][(qn) * 2 + nf] = __builtin_amdgcn_mfma_f32_16x16x32_bf16( \
            af[mf][1], bfr[nf][1], acc[(qm) * MF + mf][(qn) * 2 + nf], 0, 0, 0); \
      } \
    __builtin_amdgcn_s_setprio(0); }

#define VMCNT_GATE() do { if constexpr (BM == 256) { VMCNT(6); } else { VMCNT(4); } } while (0)

template <int MODE, int BM>
__global__ __launch_bounds__(512, 2) void gemm8(
    const u16* __restrict__ A, const u16* __restrict__ Bw, const int K, const int N,
    u16* __restrict__ qb, u16* __restrict__ kb, u16* __restrict__ vtb,
    const float* __restrict__ biasc, const float* __restrict__ cosT,
    const float* __restrict__ sinT, float* __restrict__ outf) {
  constexpr int MF = BM / 64;                   // m-frags per quadrant per wave
  constexpr int BUF = BM * 64 + 16384;          // u16 per double-buffer half
  __shared__ u16 lds[2 * BUF];                  // BM=256: 128 KiB
  const int tid = threadIdx.x;
  const int lane = tid & 63, wid = tid >> 6;
  const int wr = wid >> 2, wc = wid & 3;        // wave grid 2M x 4N
  const int col = lane & 15, rg = lane >> 4;
  const int tm = blockIdx.x, tn = blockIdx.y;

  // staging: pre-swizzled global source, linear LDS dest
  const int srow = tid >> 3;                    // 0..63
  const int scol = ((tid & 7) ^ (srow & 7)) * 8;
  const u16* aS = A + ((size_t)tm * BM + srow) * K + scol;
  const u16* bS = Bw + ((size_t)tn * 256 + srow) * K + scol;

  // swizzled ds_read offsets (u16 units); row&7 == col&7 for all frag rows
  const int koff0 = (rg ^ (col & 7)) * 8;
  const int koff1 = ((4 + rg) ^ (col & 7)) * 8;
  const int arow = wr * (BM / 4) + col;
  const int brow = wc * 32 + col;

  f32x4 acc[2 * MF][4];
#pragma unroll
  for (int i = 0; i < 2 * MF; ++i)
#pragma unroll
    for (int j = 0; j < 4; ++j) acc[i][j] = (f32x4){0.f, 0.f, 0.f, 0.f};
  bf16x8 af[MF][2], bfr[2][2];

  const int ITERS = K >> 7;             // 2 K-tiles (BK=64) per iteration

  // prologue: T0 fully, then T1.{A0,B1,A1}; T1.B0 issued at P1 of it=0
  STAGE_A(0, 0); STAGE_A(0, 1);
  STAGE_B(0, 0); STAGE_B(0, 1);
  STAGE_A(1, 0); STAGE_B(1, 1); STAGE_A(1, 1);
  VMCNT_GATE();                          // T0 landed; T1 partials in flight
  BAR();

#pragma unroll 1
  for (int it = 0; it < ITERS; ++it) {
    const int t0 = it * 2;
    const bool more = (it + 1 < ITERS);
    // P1: buf0 quadrant (0,0); stage T_{t0+1}.B0
    LDA8(0, 0); LDB8(0, 0);
    STAGE_B(t0 + 1, 0);
    MM8(0, 0); SBAR0(); BAR();
    // P2: (0,1) reuse A; stage T_{t0+2}.A0
    LDB8(0, 1);
    if (more) STAGE_A(t0 + 2, 0);
    MM8(0, 1); SBAR0(); BAR();
    // P3: (1,1) reuse B; stage T_{t0+2}.B1
    LDA8(0, 1);
    if (more) STAGE_B(t0 + 2, 1);
    MM8(1, 1); SBAR0(); BAR();
    // P4: (1,0) reuse A; stage T_{t0+2}.A1; gate buf1 reads
    LDB8(0, 0);
    if (more) STAGE_A(t0 + 2, 1);
    MM8(1, 0); SBAR0();
    if (more) { VMCNT_GATE(); } else { VMCNT(0); }
    BAR();
    // P5: buf1 quadrant (0,0); stage T_{t0+2}.B0
    LDA8(1, 0); LDB8(1, 0);
    if (more) STAGE_B(t0 + 2, 0);
    MM8(0, 0); SBAR0(); BAR();
    // P6: (0,1); stage T_{t0+3}.A0
    LDB8(1, 1);
    if (more) STAGE_A(t0 + 3, 0);
    MM8(0, 1); SBAR0(); BAR();
    // P7: (1,1); stage T_{t0+3}.B1
    LDA8(1, 1);
    if (more) STAGE_B(t0 + 3, 1);
    MM8(1, 1); SBAR0(); BAR();
    // P8: (1,0); stage T_{t0+3}.A1; gate buf0 reads
    LDB8(1, 0);
    if (more) STAGE_A(t0 + 3, 1);
    MM8(1, 0); SBAR0();
    if (more) VMCNT_GATE();
    BAR();
  }

  // epilogue (MODE 0): rows m = tm*256 + qm*128 + wr*64 + mf*16 + rg*4 + r
  //                    cols n = tn*256 + qn*128 + wc*32 + nf*16 + col
  if constexpr (MODE == 1) {
#pragma unroll
    for (int qm = 0; qm < 2; ++qm)
#pragma unroll
      for (int mf = 0; mf < MF; ++mf) {
        const int mbase = tm * BM + qm * (BM / 2) + wr * (BM / 4) + mf * 16 + rg * 4;
#pragma unroll
        for (int qn = 0; qn < 2; ++qn)
#pragma unroll
          for (int nf = 0; nf < 2; ++nf) {
            const int n = tn * 256 + qn * 128 + wc * 32 + nf * 16 + col;
#pragma unroll
            for (int r = 0; r < 4; ++r)
              outf[(size_t)(mbase + r) * N + n] = acc[qm * MF + mf][qn * 2 + nf][r];
          }
      }
  } else {
    if (tn < 8) {                       // Q heads: bias + RoPE + 0.125*log2e
      const float QS = 0.18033688011112042f;
#pragma unroll
      for (int qm = 0; qm < 2; ++qm)
#pragma unroll
        for (int qn = 0; qn < 2; ++qn) {
          const int h = tn * 4 + qn * 2 + (wc >> 1);
          const int c32 = wc & 1;
          const int n0 = tn * 256 + qn * 128 + wc * 32 + col;
          const float b1 = biasc[n0], b2 = biasc[n0 + 16];
          const int f = c32 * 16 + col;          // freq index
          const int ph0 = c32 * 32 + col;        // permuted head pos
#pragma unroll
          for (int mf = 0; mf < MF; ++mf)
#pragma unroll
            for (int r = 0; r < 4; ++r) {
              const int m = tm * 256 + qm * 128 + wr * 64 + mf * 16 + rg * 4 + r;
              const int b = m >> 11, s = m & 2047;
              const size_t base = ((size_t)(b * 32 + h) * 2048 + s) * 64;
              float x1 = acc[qm * MF + mf][qn * 2 + 0][r] + b1;
              float x2 = acc[qm * MF + mf][qn * 2 + 1][r] + b2;
              float c = cosT[m * 32 + f], sn = sinT[m * 32 + f];
              qb[base + ph0]      = f2bf((x1 * c - x2 * sn) * QS);
              qb[base + ph0 + 16] = f2bf((x2 * c + x1 * sn) * QS);
            }
        }
    } else if (tn < 10) {               // K heads
#pragma unroll
      for (int qm = 0; qm < 2; ++qm)
#pragma unroll
        for (int qn = 0; qn < 2; ++qn) {
          const int hk = (tn - 8) * 4 + qn * 2 + (wc >> 1);
          const int c32 = wc & 1;
          const int n0 = tn * 256 + qn * 128 + wc * 32 + col;
          const float b1 = biasc[n0], b2 = biasc[n0 + 16];
          const int f = c32 * 16 + col;
          const int ph0 = c32 * 32 + col;
#pragma unroll
          for (int mf = 0; mf < MF; ++mf)
#pragma unroll
            for (int r = 0; r < 4; ++r) {
              const int m = tm * 256 + qm * 128 + wr * 64 + mf * 16 + rg * 4 + r;
              const int b = m >> 11, s = m & 2047;
              const size_t base = ((size_t)(b * 8 + hk) * 2048 + s) * 64;
              float x1 = acc[qm * MF + mf][qn * 2 + 0][r] + b1;
              float x2 = acc[qm * MF + mf][qn * 2 + 1][r] + b2;
              float c = cosT[m * 32 + f], sn = sinT[m * 32 + f];
              kb[base + ph0]      = f2bf(x1 * c - x2 * sn);
              kb[base + ph0 + 16] = f2bf(x2 * c + x1 * sn);
            }
        }
    } else {                            // V heads (no rope, natural d), store [d][s]
#pragma unroll
      for (int qm = 0; qm < 2; ++qm)
#pragma unroll
        for (int qn = 0; qn < 2; ++qn)
#pragma unroll
          for (int nf = 0; nf < 2; ++nf) {
            const int n = tn * 256 + qn * 128 + wc * 32 + nf * 16 + col;
            const int hk = (n - 2560) >> 6;
            const int d = (n - 2560) & 63;
            const float bvv = biasc[n];
#pragma unroll
            for (int mf = 0; mf < MF; ++mf)
#pragma unroll
              for (int r = 0; r < 4; ++r) {
                const int m = tm * 256 + qm * 128 + wr * 64 + mf * 16 + rg * 4 + r;
                const int b = m >> 11, s = m & 2047;
                vtb[((size_t)(b * 8 + hk) * 64 + d) * 2048 + s] =
                    f2bf(acc[qm * MF + mf][qn * 2 + nf][r] + bvv);
              }
          }
    }
  }
}

// ---------- 256x128 read-ahead GEMM for O-proj (r8-proven, ~28us) ----------
#define RSTAGE_A(kt, c) GLOAD_LDS16( \
    aS + (size_t)((c) * 64) * K + (size_t)(kt) * 64, \
    lds + ((kt) & 1) * BUFSZ + (c) * 4096 + tid * 8)

#define RSTAGE_B(kt, c) GLOAD_LDS16( \
    bS + (size_t)((c) * 64) * K + (size_t)(kt) * 64, \
    lds + ((kt) & 1) * BUFSZ + 16384 + (c) * 4096 + tid * 8)

#define STAGE_H1(kt) { RSTAGE_A(kt, 0); RSTAGE_A(kt, 1); RSTAGE_A(kt, 2); }
#define STAGE_H2(kt) { RSTAGE_A(kt, 3); RSTAGE_B(kt, 0); RSTAGE_B(kt, 1); }

#define RLDA(dst, buf, kof) { \
    const u16* p_ = lds + (buf) * BUFSZ + arow * 64; \
    _Pragma("unroll") \
    for (int mf = 0; mf < 4; ++mf) dst[mf] = *(const bf16x8*)(p_ + mf * 1024 + (kof)); }

#define RLDB(dst, buf, kof) { \
    const u16* p_ = lds + (buf) * BUFSZ + 16384 + brow * 64; \
    _Pragma("unroll") \
    for (int nf = 0; nf < 4; ++nf) dst[nf] = *(const bf16x8*)(p_ + nf * 1024 + (kof)); }

#define RMM(afs, bfs) { \
    __builtin_amdgcn_s_setprio(1); \
    _Pragma("unroll") \
    for (int mf = 0; mf < 4; ++mf) \
      _Pragma("unroll") \
      for (int nf = 0; nf < 4; ++nf) \
        acc[mf][nf] = __builtin_amdgcn_mfma_f32_16x16x32_bf16(afs[mf], bfs[nf], acc[mf][nf], 0, 0, 0); \
    __builtin_amdgcn_s_setprio(0); }

__global__ void __launch_bounds__(512)
__attribute__((amdgpu_waves_per_eu(2, 2)))
gemm_o(const u16* __restrict__ A, const u16* __restrict__ Bw, const int K, const int N,
       float* __restrict__ outf) {
  constexpr int BUFSZ = (256 + 128) * 64;   // u16 per buffer (48 KiB)
  __shared__ u16 lds[2 * BUFSZ];            // 96 KiB
  const int tid = threadIdx.x;
  const int lane = tid & 63, wid = tid >> 6;
  const int wr = wid >> 1, wc = wid & 1;    // wave grid 4M x 2N
  const int col = lane & 15, rg = lane >> 4;
  const int tm = blockIdx.x, tn = blockIdx.y;

  // staging: pre-swizzled global source, linear LDS dest (64x64 chunks)
  const int srow = tid >> 3;                // 0..63
  const int scol = ((tid & 7) ^ (srow & 7)) * 8;
  const u16* aS = A + ((size_t)tm * 256 + srow) * K + scol;
  const u16* bS = Bw + ((size_t)tn * 128 + srow) * K + scol;

  // swizzled ds_read offsets (u16); row&7 == col&7 for all frag rows
  const int koff0 = (rg ^ (col & 7)) * 8;        // k-half 0
  const int koff1 = ((4 + rg) ^ (col & 7)) * 8;  // k-half 1
  const int arow = wr * 64 + col;
  const int brow = wc * 64 + col;

  f32x4 acc[4][4];
#pragma unroll
  for (int i = 0; i < 4; ++i)
#pragma unroll
    for (int j = 0; j < 4; ++j) acc[i][j] = (f32x4){0.f, 0.f, 0.f, 0.f};
  bf16x8 aX[4], aY[4], bA[4], bB[4];        // read-ahead frag double-buffer

  const int ITERS = K >> 7;                 // 2 K-tiles (BK=64) per iteration

  // prologue: stage T0+T1 fully; counted wait for T0; read P1 frags
  STAGE_H1(0); STAGE_H2(0); STAGE_H1(1); STAGE_H2(1);
  VMCNT(6);
  BAR();
  RLDA(aX, 0, koff0); RLDB(bA, 0, koff0);

#pragma unroll 1
  for (int it = 0; it < ITERS; ++it) {
    const bool more = (it + 1 < ITERS);
    // P1: MM(b0,k0); rd b0k1; finish staging tile 2it+1 (2nd half)
    if (it > 0) STAGE_H2(2 * it + 1);
    RLDA(aY, 0, koff1); RLDB(bB, 0, koff1);
    RMM(aX, bA);
    LG0(); VMCNT(0); BAR();
    // P2: MM(b0,k1); rd b1k0; stage tile 2it+2 1st half
    if (more) STAGE_H1(2 * it + 2);
    RLDA(aX, 1, koff0); RLDB(bA, 1, koff0);
    RMM(aY, bB);
    LG0(); BAR();
    // P3: MM(b1,k0); rd b1k1; stage tile 2it+2 2nd half
    if (more) STAGE_H2(2 * it + 2);
    RLDA(aY, 1, koff1); RLDB(bB, 1, koff1);
    RMM(aX, bA);
    LG0();
    if (more) VMCNT(0);
    BAR();
    // P4: MM(b1,k1); rd b0'k0; stage tile 2it+3 1st half
    if (more) {
      STAGE_H1(2 * it + 3);
      RLDA(aX, 0, koff0); RLDB(bA, 0, koff0);
    }
    RMM(aY, bB);
    LG0(); BAR();
  }

  // epilogue: m = tm*256 + wr*64 + mf*16 + rg*4 + r
  //           n = tn*128 + wc*64 + nf*16 + col
#pragma unroll
  for (int mf = 0; mf < 4; ++mf) {
    const int mbase = tm * 256 + wr * 64 + mf * 16 + rg * 4;
#pragma unroll
    for (int nf = 0; nf < 4; ++nf) {
      const int n = tn * 128 + wc * 64 + nf * 16 + col;
#pragma unroll
      for (int r = 0; r < 4; ++r)
        outf[(size_t)(mbase + r) * N + n] = acc[mf][nf][r];
    }
  }
}

// ---------- flash attention r18: QK(A)->QK(B)->PV(A)->PV(B) interleave ----------
// r15/r16 post-mortem: pairing bought ~0 because the allocator voluntarily
// targeted 64 VGPR (8 waves/SIMD heuristic) -> two tiles' temporaries can't
// be live at once -> serialized to recycle registers (r16's explicit split
// spilled AT 64). Fix: (1) amdgpu_waves_per_eu(4,4) pins the target at 4
// waves/SIMD = the occupancy launch_bounds(256,4) implies anyway -> 128-reg
// budget actually usable; (2) source-level phase split: QK(B)'s MFMAs are
// data-independent of tile A, so issuing QK(A), QK(B), PV(A), PV(B) fills
// A's exp2/pack/PV latency with B's work; only the po chain (~160cyc)
// serializes the PVs. Same math, LDS, barriers as r15 (verified).
#define ATTN_QK(kv0v, Kb, paq0, paq1) { \
      const bool diag = ((kv0v) + 32 > q0w); \
      f32x16 t = z16(); \
      _Pragma("unroll") \
      for (int s = 0; s < 4; ++s) { \
        bf16x8 kf = *(const bf16x8*)&(Kb)[SW(q32, s * 16 + hl * 8)]; \
        t = __builtin_amdgcn_mfma_f32_32x32x16_bf16(kf, qf[s], t, 0, 0, 0); \
      } \
      if (diag) { \
        const int qg = q0w + q32; \
        _Pragma("unroll") \
        for (int r = 0; r < 16; ++r) { \
          const int kvg = (kv0v) + (r & 3) + 8 * (r >> 2) + h4; \
          if (kvg > qg) t[r] = -1e30f; \
        } \
      } \
      _Pragma("unroll") \
      for (int r = 0; r < 16; ++r) t[r] = __builtin_amdgcn_exp2f(t[r]); \
      l_part += (((t[0] + t[1]) + (t[2] + t[3])) + ((t[4] + t[5]) + (t[6] + t[7]))) + \
                (((t[8] + t[9]) + (t[10] + t[11])) + ((t[12] + t[13]) + (t[14] + t[15]))); \
      unsigned pw0, pw1, pw2, pw3, pw4, pw5, pw6, pw7; \
      asm("v_cvt_pk_bf16_f32 %0, %1, %2" : "=v"(pw0) : "v"(t[0]), "v"(t[1])); \
      asm("v_cvt_pk_bf16_f32 %0, %1, %2" : "=v"(pw1) : "v"(t[2]), "v"(t[3])); \
      asm("v_cvt_pk_bf16_f32 %0, %1, %2" : "=v"(pw2) : "v"(t[4]), "v"(t[5])); \
      asm("v_cvt_pk_bf16_f32 %0, %1, %2" : "=v"(pw3) : "v"(t[6]), "v"(t[7])); \
      asm("v_cvt_pk_bf16_f32 %0, %1, %2" : "=v"(pw4) : "v"(t[8]), "v"(t[9])); \
      asm("v_cvt_pk_bf16_f32 %0, %1, %2" : "=v"(pw5) : "v"(t[10]), "v"(t[11])); \
      asm("v_cvt_pk_bf16_f32 %0, %1, %2" : "=v"(pw6) : "v"(t[12]), "v"(t[13])); \
      asm("v_cvt_pk_bf16_f32 %0, %1, %2" : "=v"(pw7) : "v"(t[14]), "v"(t[15])); \
      asm("v_permlane32_swap_b32 %0, %1" : "+v"(pw0), "+v"(pw2)); \
      asm("v_permlane32_swap_b32 %0, %1" : "+v"(pw1), "+v"(pw3)); \
      asm("v_permlane32_swap_b32 %0, %1" : "+v"(pw4), "+v"(pw6)); \
      asm("v_permlane32_swap_b32 %0, %1" : "+v"(pw5), "+v"(pw7)); \
      paq0 = __builtin_bit_cast(bf16x8, (u32x4){pw0, pw1, pw2, pw3}); \
      paq1 = __builtin_bit_cast(bf16x8, (u32x4){pw4, pw5, pw6, pw7}); \
    }

#define ATTN_PV(Vb, paq0, paq1) { \
      _Pragma("unroll") \
      for (int dblk = 0; dblk < 2; ++dblk) { \
        const int d = dblk * 32 + q32; \
        const int vr = d >> 1, vc = (d & 1) * 32 + hl * 8; \
        bf16x8 v0 = *(const bf16x8*)&(Vb)[SW(vr, vc)]; \
        bf16x8 v1 = *(const bf16x8*)&(Vb)[SW(vr, vc + 16)]; \
        po[dblk] = __builtin_amdgcn_mfma_f32_32x32x16_bf16(paq0, v0, po[dblk], 0, 0, 0); \
        po[dblk] = __builtin_amdgcn_mfma_f32_32x32x16_bf16(paq1, v1, po[dblk], 0, 0, 0); \
      } \
    }

__global__ __launch_bounds__(256, 4)
__attribute__((amdgpu_waves_per_eu(4, 4)))
void attn_k(
    const u16* __restrict__ qb, const u16* __restrict__ kb,
    const u16* __restrict__ vtb, u16* __restrict__ attb) {
  __shared__ __align__(16) u16 Kl[2][2][2048];   // [slot][tile01][32 kv][64 d] swizzled
  __shared__ __align__(16) u16 Vl[2][2][2048];   // [slot][tile01] paired (d,kv) layout
  const int tid = threadIdx.x, lane = tid & 63, w = tid >> 6;  // w in 0..3
  const int q32 = lane & 31, hl = lane >> 5, h4 = hl * 4;

  const int bid = blockIdx.x;                       // 1024 blocks
  const int xcd = bid & 7, pos = bid >> 3;          // XCD-chunked
  const int grp = xcd * 8 + (pos >> 4);             // 8 (b,h) per XCD (L2-fit)
  const int s0 = pos & 15;
  const int strip = ((pos >> 5) & 1) ? (15 - s0) : s0;  // CU-complementary strips
  const int h = grp & 31, b = grp >> 5;
  const int qb0 = (15 - strip) * 128;               // longest strips at strip=0
  const int hk = h >> 2;
  const int q0w = qb0 + w * 32;                     // this wave's 32 rows

  // Q B-frags (QK^T B-operand): lane holds Q[q0w+q32][s*16 + hl*8 .. +7]
  const u16* Qp = qb + ((size_t)(b * 32 + h) * 2048 + q0w + q32) * 64 + hl * 8;
  bf16x8 qf[4];
#pragma unroll
  for (int s = 0; s < 4; ++s) qf[s] = *(const bf16x8*)(Qp + s * 16);

  f32x16 po[2];                          // O[q=crow(r,hl)][d=dblk*32+q32]
  po[0] = z16(); po[1] = z16();
  float l_part = 0.f;                    // softmax denom partial, q = q32

  const u16* Kbase = kb + (size_t)(b * 8 + hk) * 2048 * 64;
  const u16* Vbase = vtb + (size_t)(b * 8 + hk) * 64 * 2048;
  const int srow = tid >> 3, c8 = (tid & 7) << 3;
  const int cs = c8 ^ ((srow & 7) << 3);
  const u16* Ksrc = Kbase + (size_t)srow * 64 + cs;                         // +kv0*64/tile
  const u16* Vsrc = Vbase + (size_t)(srow * 2 + (cs >> 5)) * 2048 + (cs & 31);  // +kv0/tile
  char* Kdst0 = (char*)Kl + w * 1024;    // wave's quarter of each 4KB tile
  char* Vdst0 = (char*)Vl + w * 1024;

  const int nkv = (qb0 >> 5) + 4;        // always even (qb0 multiple of 128)
  const int npairs = nkv >> 1;
  const int rowmax = q0w + 31;

  // prologue: stage pair 0 (tiles 0,1) into slot 0
  GLOAD_LDS16(Ksrc, Kdst0);
  GLOAD_LDS16(Vsrc, Vdst0);
  GLOAD_LDS16(Ksrc + 2048, Kdst0 + 4096);
  GLOAD_LDS16(Vsrc + 32, Vdst0 + 4096);

  for (int p = 0; p < npairs; ++p) {
    const int slot = p & 1;
    if (p + 1 < npairs) {                // stage pair p+1 into slot (p+1)&1
      const int s1 = (p + 1) & 1;        // (= slot of pair p-1, retired at
      const int t0 = 2 * p + 2;          //  the end-barrier of iter p-1)
      GLOAD_LDS16(Ksrc + (size_t)t0 * 2048, Kdst0 + s1 * 8192);
      GLOAD_LDS16(Vsrc + (size_t)t0 * 32, Vdst0 + s1 * 8192);
      GLOAD_LDS16(Ksrc + (size_t)(t0 + 1) * 2048, Kdst0 + s1 * 8192 + 4096);
      GLOAD_LDS16(Vsrc + (size_t)(t0 + 1) * 32, Vdst0 + s1 * 8192 + 4096);
      VMCNT(4);                          // pair p landed (1 younger pair in flight)
    } else {
      VMCNT(0);
    }
    BAR();                               // all waves' pair-p loads landed

    const int kvA = 2 * p * 32;
    const int kvB = kvA + 32;
    const u16* KbA = &Kl[slot][0][0];
    const u16* VbA = &Vl[slot][0][0];
    const u16* KbB = &Kl[slot][1][0];
    const u16* VbB = &Vl[slot][1][0];
    const bool doA = (kvA <= rowmax), doB = (kvB <= rowmax);

    bf16x8 paA0, paA1, paB0, paB1;
    __builtin_amdgcn_s_setprio(1);
    if (doA) ATTN_QK(kvA, KbA, paA0, paA1);
    if (doB) ATTN_QK(kvB, KbB, paB0, paB1);
    if (doA) ATTN_PV(VbA, paA0, paA1);
    if (doB) ATTN_PV(VbB, paB0, paB1);
    __builtin_amdgcn_s_setprio(0);

    SBAR0();
    BAR();                               // readers done; slot may be restaged
  }

  // epilogue: l_full(lane) = denom for q=q32 (partner half holds other kv)
  const float l_full = l_part + __shfl_xor(l_part, 32);
#pragma unroll
  for (int r = 0; r < 16; ++r) {
    const int qrl = (r & 3) + 8 * (r >> 2) + h4;      // local q row of po[.][r]
    const float lq = __shfl(l_full, qrl);             // lane qrl holds l[qrl]
    const float inv = 1.f / lq;
    const size_t base = ((size_t)b * 2048 + q0w + qrl) * 2048 + h * 64;
    attb[base + q32]      = f2bf(po[0][r] * inv);
    attb[base + 32 + q32] = f2bf(po[1][r] * inv);
  }
}

// ---------- launch ----------
extern "C" void kernel_launch(void* const* d_in, const int* in_sizes, int n_in,
                              void* d_out, int out_size, void* d_ws, size_t ws_size,
                              hipStream_t stream) {
  const float* hs = (const float*)d_in[0];
  const int* pos = (const int*)d_in[1];
  const float* Wq = (const float*)d_in[2];
  const float* bq = (const float*)d_in[3];
  const float* Wk = (const float*)d_in[4];
  const float* bk = (const float*)d_in[5];
  const float* Wv = (const float*)d_in[6];
  const float* bv = (const float*)d_in[7];
  const float* Wo = (const float*)d_in[8];
  float* out = (float*)d_out;

  char* ws = (char*)d_ws;
  size_t off = 0;
  u16* hsb = (u16*)(ws + off);   off += (size_t)4096 * 2048 * 2;
  u16* wqkvb = (u16*)(ws + off); off += (size_t)3072 * 2048 * 2;
  u16* wob = (u16*)(ws + off);   off += (size_t)2048 * 2048 * 2;
  float* biasc = (float*)(ws + off); off += 3072 * 4;
  float* cosT = (float*)(ws + off);  off += (size_t)4096 * 32 * 4;
  float* sinT = (float*)(ws + off);  off += (size_t)4096 * 32 * 4;
  u16* qb = (u16*)(ws + off);    off += (size_t)2 * 32 * 2048 * 64 * 2;
  u16* kb = (u16*)(ws + off);    off += (size_t)2 * 8 * 2048 * 64 * 2;
  u16* vtb = (u16*)(ws + off);   off += (size_t)2 * 8 * 64 * 2048 * 2;
  u16* attb = (u16*)(ws + off);  off += (size_t)4096 * 2048 * 2;

  prep_all<<<18956, 256, 0, stream>>>((const f32x4v*)hs, (u16x4*)hsb,
                                      (const f32x4v*)Wq, (const f32x4v*)Wk,
                                      (const f32x4v*)Wv, (u16x4*)wqkvb,
                                      (const f32x4v*)Wo, (u16x4*)wob,
                                      pos, cosT, sinT, bq, bk, bv, biasc);

  gemm8<0, 256><<<dim3(16, 12), 512, 0, stream>>>(hsb, wqkvb, 2048, 3072,
                                                  qb, kb, vtb, biasc, cosT, sinT, nullptr);
  attn_k<<<1024, 256, 0, stream>>>(qb, kb, vtb, attb);
  gemm_o<<<dim3(16, 16), 512, 0, stream>>>(attb, wob, 2048, 2048, out);
}